// Round 5
// baseline (493.450 us; speedup 1.0000x reference)
//
#include <hip/hip_runtime.h>
#include <hip/hip_bf16.h>
#include <math.h>

#define N_NODES 10000
#define N_EDGES 64000
#define H 128
#define L 8
#define NL (N_NODES * L)

typedef __attribute__((ext_vector_type(4))) float f32x4;
typedef __attribute__((ext_vector_type(8))) __bf16 bf16x8;

__device__ __forceinline__ float silu_f(float x) { return x / (1.f + __expf(-x)); }

// ---------------- LayerNorm: one wave per node ----------------
__global__ __launch_bounds__(256) void ln_kernel(const float* __restrict__ x,
                                                 const float* __restrict__ g,
                                                 const float* __restrict__ b,
                                                 float* __restrict__ out, int n_nodes) {
  int wave = threadIdx.x >> 6;
  int lane = threadIdx.x & 63;
  int n = blockIdx.x * 4 + wave;
  if (n >= n_nodes) return;
  const float* xr = x + (size_t)n * H;
  float a0 = xr[lane], a1 = xr[lane + 64];
  float s = a0 + a1;
#pragma unroll
  for (int off = 32; off >= 1; off >>= 1) s += __shfl_xor(s, off, 64);
  float mu = s * (1.f / H);
  float d0 = a0 - mu, d1 = a1 - mu;
  float v = d0 * d0 + d1 * d1;
#pragma unroll
  for (int off = 32; off >= 1; off >>= 1) v += __shfl_xor(v, off, 64);
  float rstd = rsqrtf(v * (1.f / H) + 1e-5f);
  float* orow = out + (size_t)n * H;
  orow[lane] = d0 * rstd * g[lane] + b[lane];
  orow[lane + 64] = d1 * rstd * g[lane + 64] + b[lane + 64];
}

// ---------------- vecw = vec * vln_w  -> bf16 ----------------
__global__ __launch_bounds__(256) void vecw_kernel(const float* __restrict__ vec,
                                                   const float* __restrict__ w,
                                                   __bf16* __restrict__ out, size_t total8) {
  size_t i = (size_t)blockIdx.x * blockDim.x + threadIdx.x;
  size_t stride = (size_t)gridDim.x * blockDim.x;
  for (; i < total8; i += stride) {
    size_t base = i * 8;
    f32x4 a = *(const f32x4*)(vec + base);
    f32x4 b = *(const f32x4*)(vec + base + 4);
    int c = (int)(base & 127);
    bf16x8 h;
    h[0] = (__bf16)(a[0] * w[c + 0]); h[1] = (__bf16)(a[1] * w[c + 1]);
    h[2] = (__bf16)(a[2] * w[c + 2]); h[3] = (__bf16)(a[3] * w[c + 3]);
    h[4] = (__bf16)(b[0] * w[c + 4]); h[5] = (__bf16)(b[1] * w[c + 5]);
    h[6] = (__bf16)(b[2] * w[c + 6]); h[7] = (__bf16)(b[3] * w[c + 7]);
    *(bf16x8*)(out + base) = h;
  }
}

// ---------------- weight convert into one [2048][128] bf16 table ----------------
// col map: [0,384) Wvec | [384,512) Wtrg | [512,640) Wsrc | [640,768) Wq | [768,896) Wk
//          | [896,1024) Wv | [1024,1152) Wdk | [1152,1280) Wdv | [1280,1408) Wf
//          | [1408,1664) Ws | [1664,2048) Wo
__global__ __launch_bounds__(256) void wconv_kernel(
    const float* __restrict__ Wvec, const float* __restrict__ Wq, const float* __restrict__ Wk,
    const float* __restrict__ Wv, const float* __restrict__ Wdk, const float* __restrict__ Wdv,
    const float* __restrict__ Ws, const float* __restrict__ Wtrg, const float* __restrict__ Wsrc,
    const float* __restrict__ Wf, const float* __restrict__ Wo,
    const float* __restrict__ bq, const float* __restrict__ bk, const float* __restrict__ bv,
    const float* __restrict__ bdk, const float* __restrict__ bdv, const float* __restrict__ bf,
    __bf16* __restrict__ Wt, float* __restrict__ bqkv, float* __restrict__ bfm) {
  int bid = blockIdx.x;
  int t = threadIdx.x;
  if (bid >= 256) {
    if (bid == 256) {
      if (t < 128) { bqkv[t] = bq[t]; bqkv[128 + t] = bk[t]; bqkv[256 + t] = bv[t]; }
    } else {
      if (t < 128) { bfm[t] = bdk[t]; bfm[128 + t] = bdv[t]; bfm[256 + t] = bf[t]; }
    }
    return;
  }
  int ct = bid >> 2, kt = bid & 3;
  int gc0 = ct * 32;
  const float* W; int ldw, sc0;
  if      (gc0 < 384)  { W = Wvec; ldw = 384; sc0 = gc0; }
  else if (gc0 < 512)  { W = Wtrg; ldw = 128; sc0 = gc0 - 384; }
  else if (gc0 < 640)  { W = Wsrc; ldw = 128; sc0 = gc0 - 512; }
  else if (gc0 < 768)  { W = Wq;   ldw = 128; sc0 = gc0 - 640; }
  else if (gc0 < 896)  { W = Wk;   ldw = 128; sc0 = gc0 - 768; }
  else if (gc0 < 1024) { W = Wv;   ldw = 128; sc0 = gc0 - 896; }
  else if (gc0 < 1152) { W = Wdk;  ldw = 128; sc0 = gc0 - 1024; }
  else if (gc0 < 1280) { W = Wdv;  ldw = 128; sc0 = gc0 - 1152; }
  else if (gc0 < 1408) { W = Wf;   ldw = 128; sc0 = gc0 - 1280; }
  else if (gc0 < 1664) { W = Ws;   ldw = 256; sc0 = gc0 - 1408; }
  else                 { W = Wo;   ldw = 384; sc0 = gc0 - 1664; }
  __shared__ float tile[32][33];
  int tx = t & 31, ty = t >> 5;
#pragma unroll
  for (int i = 0; i < 4; ++i)
    tile[ty + i * 8][tx] = W[(size_t)(kt * 32 + ty + i * 8) * ldw + sc0 + tx];
  __syncthreads();
#pragma unroll
  for (int i = 0; i < 4; ++i)
    Wt[(size_t)(gc0 + ty + i * 8) * 128 + kt * 32 + tx] = (__bf16)tile[tx][ty + i * 8];
}

// ---------------- MFMA GEMM v2: C[M,Nn] = act(A[M,128] @ Bt^T + bias) ----------------
// As only in LDS (32KB, swizzled); B direct global->reg (L2-hot weights); no inner barriers.
// bf16-A path uses global_load_lds w/ pre-swizzled source — requires M % 128 == 0 (callers ok).
template <typename AT, typename CT>
__global__ __launch_bounds__(256, 3) void gemm_v2(const AT* __restrict__ A,
                                                  const __bf16* __restrict__ Bt,
                                                  const float* __restrict__ bias,
                                                  CT* __restrict__ C, int M, int Nn, int ldc,
                                                  int act) {
  __shared__ __bf16 As[128 * 128];
  const int tid = threadIdx.x;
  const int lane = tid & 63;
  const int wave = tid >> 6;
  const int wm = wave >> 1, wn = wave & 1;
  const int row0 = blockIdx.x * 128;

  if constexpr (sizeof(AT) == 2) {
#pragma unroll
    for (int i = 0; i < 8; ++i) {
      int c = tid + i * 256;  // 16B chunk index; LDS dest linear (lane-contiguous)
      int row = c >> 4, k8 = c & 15;
      int k8s = k8 ^ (row & 7);  // inverse-swizzled source == read-side XOR (involution)
      const AT* src = A + (size_t)(row0 + row) * 128 + k8s * 8;
      __builtin_amdgcn_global_load_lds((const __attribute__((address_space(1))) void*)src,
                                       (__attribute__((address_space(3))) void*)(As + c * 8),
                                       16, 0, 0);
    }
  } else {
#pragma unroll
    for (int i = 0; i < 8; ++i) {
      int c = tid + i * 256;
      int row = c >> 4, k8 = c & 15;
      int gm = row0 + row;
      bf16x8 h = {};
      if (gm < M) {
        f32x4 f0 = *(const f32x4*)(A + (size_t)gm * 128 + k8 * 8);
        f32x4 f1 = *(const f32x4*)(A + (size_t)gm * 128 + k8 * 8 + 4);
        h[0] = (__bf16)f0[0]; h[1] = (__bf16)f0[1]; h[2] = (__bf16)f0[2]; h[3] = (__bf16)f0[3];
        h[4] = (__bf16)f1[0]; h[5] = (__bf16)f1[1]; h[6] = (__bf16)f1[2]; h[7] = (__bf16)f1[3];
      }
      int byte = (c * 16) ^ ((row & 7) << 4);
      *(bf16x8*)((char*)As + byte) = h;
    }
  }
  __syncthreads();

  const int ncTiles = Nn >> 7;
  for (int ct = 0; ct < ncTiles; ++ct) {
    f32x4 acc[4][4];
#pragma unroll
    for (int mi = 0; mi < 4; ++mi)
#pragma unroll
      for (int ni = 0; ni < 4; ++ni) acc[mi][ni] = f32x4{0.f, 0.f, 0.f, 0.f};

    const __bf16* Bbase =
        Bt + ((size_t)(ct * 128 + wn * 64 + (lane & 15)) << 7) + ((lane >> 4) << 3);
#pragma unroll
    for (int ks = 0; ks < 4; ++ks) {
      bf16x8 b[4];
#pragma unroll
      for (int ni = 0; ni < 4; ++ni) b[ni] = *(const bf16x8*)(Bbase + (ni << 11) + (ks << 5));
      bf16x8 a[4];
#pragma unroll
      for (int mi = 0; mi < 4; ++mi) {
        int row = wm * 64 + mi * 16 + (lane & 15);
        int byte = (row * 256 + ks * 64 + ((lane >> 4) << 4)) ^ ((row & 7) << 4);
        a[mi] = *(const bf16x8*)((const char*)As + byte);
      }
#pragma unroll
      for (int mi = 0; mi < 4; ++mi)
#pragma unroll
        for (int ni = 0; ni < 4; ++ni)
          acc[mi][ni] =
              __builtin_amdgcn_mfma_f32_16x16x32_bf16(a[mi], b[ni], acc[mi][ni], 0, 0, 0);
    }

#pragma unroll
    for (int mi = 0; mi < 4; ++mi) {
      int rbase = row0 + wm * 64 + mi * 16 + ((lane >> 4) << 2);
#pragma unroll
      for (int ni = 0; ni < 4; ++ni) {
        int gcol = ct * 128 + wn * 64 + ni * 16 + (lane & 15);
        float bv = bias ? bias[gcol] : 0.f;
#pragma unroll
        for (int r = 0; r < 4; ++r) {
          int grow = rbase + r;
          if (grow < M) {
            float xv = acc[mi][ni][r] + bv;
            if (act) xv = silu_f(xv);
            C[(size_t)grow * ldc + gcol] = (CT)xv;
          }
        }
      }
    }
  }
}

// ---------------- vec_dot reduce (t12 = big cols 0..255, row stride 640) ----------------
__global__ __launch_bounds__(256) void vecdot_kernel(const __bf16* __restrict__ big,
                                                     float* __restrict__ vdot, int n_nodes) {
  int n = blockIdx.x * 2 + (threadIdx.x >> 7);
  int h = threadIdx.x & 127;
  if (n >= n_nodes) return;
  const __bf16* base = big + (size_t)n * 8 * 640;
  float acc = 0.f;
#pragma unroll
  for (int l = 0; l < 8; l++)
    acc += (float)base[l * 640 + h] * (float)base[l * 640 + 128 + h];
  vdot[(size_t)n * H + h] = acc;
}

// ---------------- message: attn + vm per edge (dkdv = fm cols 0..255, stride 384) ----------------
__global__ __launch_bounds__(256) void msg_kernel(const float* __restrict__ qkv,
                                                  const __bf16* __restrict__ fm,
                                                  const float* __restrict__ r_ij,
                                                  const int* __restrict__ ei,
                                                  __bf16* __restrict__ vm) {
  int e = blockIdx.x * 2 + (threadIdx.x >> 7);
  int h = threadIdx.x & 127;
  int src = ei[e], dst = ei[N_EDGES + e];
  float qv = qkv[(size_t)dst * 384 + h];
  float kv = qkv[(size_t)src * 384 + 128 + h];
  float vv = qkv[(size_t)src * 384 + 256 + h];
  float t = qv * kv * (float)fm[(size_t)e * 384 + h];
#pragma unroll
  for (int off = 8; off >= 1; off >>= 1) t += __shfl_xor(t, off, 16);
  float r = r_ij[e];
  float cut = 0.5f * (__cosf(0.6283185307f * r) + 1.f);
  cut = (r < 5.f) ? cut : 0.f;
  float attn = silu_f(t) * cut;
  vm[(size_t)e * H + h] = (__bf16)(vv * (float)fm[(size_t)e * 384 + 128 + h] * attn);
}

// ---------------- CSR build: histogram, scan, fill ----------------
__global__ __launch_bounds__(256) void hist_kernel(const int* __restrict__ ei,
                                                   int* __restrict__ cnt) {
  int e = blockIdx.x * 256 + threadIdx.x;
  if (e < N_EDGES) atomicAdd(&cnt[ei[N_EDGES + e]], 1);
}

__global__ __launch_bounds__(1024) void scan_kernel(const int* __restrict__ cnt,
                                                    int* __restrict__ rowptr) {
  __shared__ int wsum[16];
  int t = threadIdx.x;
  int base = t * 10;
  int local[10];
  int s = 0;
#pragma unroll
  for (int i = 0; i < 10; ++i) {
    int v = (base + i < N_NODES) ? cnt[base + i] : 0;
    local[i] = s;
    s += v;
  }
  int lane = t & 63, wave = t >> 6;
  int inc = s;
#pragma unroll
  for (int off = 1; off < 64; off <<= 1) {
    int u = __shfl_up(inc, off, 64);
    if (lane >= off) inc += u;
  }
  if (lane == 63) wsum[wave] = inc;
  __syncthreads();
  if (t == 0) {
    int acc = 0;
#pragma unroll
    for (int w = 0; w < 16; ++w) { int v = wsum[w]; wsum[w] = acc; acc += v; }
  }
  __syncthreads();
  int excl = inc - s + wsum[wave];
#pragma unroll
  for (int i = 0; i < 10; ++i)
    if (base + i <= N_NODES) rowptr[base + i] = excl + local[i];
}

__global__ __launch_bounds__(256) void fill_kernel(const int* __restrict__ ei,
                                                   const int* __restrict__ rowptr,
                                                   int* __restrict__ cursor,
                                                   int* __restrict__ elist) {
  int e = blockIdx.x * 256 + threadIdx.x;
  if (e < N_EDGES) {
    int d = ei[N_EDGES + e];
    int p = atomicAdd(&cursor[d], 1);
    elist[rowptr[d] + p] = e;
  }
}

// ---------------- gather: x_agg = Σ vm ; dvec = Σ vec_m (no atomics) ----------------
__global__ __launch_bounds__(256) void gather_kernel(const __bf16* __restrict__ vm,
                                                     const __bf16* __restrict__ s,
                                                     const __bf16* __restrict__ vecw,
                                                     const float* __restrict__ d_ij,
                                                     const int* __restrict__ ei,
                                                     const int* __restrict__ rowptr,
                                                     const int* __restrict__ elist,
                                                     float* __restrict__ x_agg,
                                                     float* __restrict__ dvec) {
  int n = blockIdx.x * 2 + (threadIdx.x >> 7);
  int h = threadIdx.x & 127;
  if (n >= N_NODES) return;
  int beg = rowptr[n], end = rowptr[n + 1];
  float ax = 0.f;
  float av[L] = {};
  for (int p = beg; p < end; ++p) {
    int e = elist[p];
    int src = ei[e];
    ax += (float)vm[(size_t)e * H + h];
    float s1 = (float)s[(size_t)e * 256 + h];
    float s2 = (float)s[(size_t)e * 256 + 128 + h];
    const __bf16* vrow = vecw + (size_t)src * L * H + h;
    const float* dd = d_ij + (size_t)e * L;
#pragma unroll
    for (int l = 0; l < L; l++) av[l] += (float)vrow[l * H] * s1 + s2 * dd[l];
  }
  x_agg[(size_t)n * H + h] = ax;
  float* drow = dvec + (size_t)n * L * H + h;
#pragma unroll
  for (int l = 0; l < L; l++) drow[l * H] = av[l];
}

// ---------------- edge update (vt = big cols 384..511, vs = cols 512..639; dfw = fm cols 256..383) ----------------
__global__ __launch_bounds__(256) void edgeupd_kernel(const __bf16* __restrict__ big,
                                                      const float* __restrict__ d_ij,
                                                      const __bf16* __restrict__ fm,
                                                      const int* __restrict__ ei,
                                                      float* __restrict__ df) {
  int e = blockIdx.x * 2 + (threadIdx.x >> 7);
  int h = threadIdx.x & 127;
  int src = ei[e], dst = ei[N_EDGES + e];
  float d[L];
  float sd2 = 0.f;
#pragma unroll
  for (int l = 0; l < L; l++) {
    d[l] = d_ij[(size_t)e * L + l];
    sd2 += d[l] * d[l];
  }
  const __bf16* arow = big + (size_t)dst * 8 * 640 + 384 + h;
  const __bf16* brow = big + (size_t)src * 8 * 640 + 512 + h;
  float dot = 0.f, p1 = 0.f, p2 = 0.f;
#pragma unroll
  for (int l = 0; l < L; l++) {
    float a = (float)arow[l * 640], bb = (float)brow[l * 640];
    dot += a * bb;
    p1 += a * d[l];
    p2 += bb * d[l];
  }
  float wdot = dot - p1 * p2 * (2.f - sd2);
  df[(size_t)e * H + h] = (float)fm[(size_t)e * 384 + 256 + h] * wdot;
}

// ---------------- final node update (vec3 = big cols 256..383) ----------------
__global__ __launch_bounds__(256) void final_kernel(const float* __restrict__ o,
                                                    const float* __restrict__ vdot,
                                                    const __bf16* __restrict__ big,
                                                    float* __restrict__ dx,
                                                    float* __restrict__ dvec, int n_nodes) {
  int n = blockIdx.x * 2 + (threadIdx.x >> 7);
  int h = threadIdx.x & 127;
  if (n >= n_nodes) return;
  float o1 = o[(size_t)n * 384 + h];
  float o2 = o[(size_t)n * 384 + 128 + h];
  float o3 = o[(size_t)n * 384 + 256 + h];
  dx[(size_t)n * H + h] = vdot[(size_t)n * H + h] * o2 + o3;
  float* drow = dvec + (size_t)n * L * H + h;
  const __bf16* v3 = big + (size_t)n * 8 * 640 + 256 + h;
#pragma unroll
  for (int l = 0; l < L; l++) drow[l * H] += (float)v3[l * 640] * o1;
}

extern "C" void kernel_launch(void* const* d_in, const int* in_sizes, int n_in, void* d_out,
                              int out_size, void* d_ws, size_t ws_size, hipStream_t stream) {
  const float* x = (const float*)d_in[0];
  const float* vec = (const float*)d_in[1];
  const float* f_ij = (const float*)d_in[2];
  const float* d_ij = (const float*)d_in[3];
  const float* r_ij = (const float*)d_in[4];
  const int* ei = (const int*)d_in[5];
  const float* ln_g = (const float*)d_in[6];
  const float* ln_b = (const float*)d_in[7];
  const float* vln_w = (const float*)d_in[8];
  const float* W_vec = (const float*)d_in[9];
  const float* W_q = (const float*)d_in[10];
  const float* b_q = (const float*)d_in[11];
  const float* W_k = (const float*)d_in[12];
  const float* b_k = (const float*)d_in[13];
  const float* W_v = (const float*)d_in[14];
  const float* b_v = (const float*)d_in[15];
  const float* W_dk = (const float*)d_in[16];
  const float* b_dk = (const float*)d_in[17];
  const float* W_dv = (const float*)d_in[18];
  const float* b_dv = (const float*)d_in[19];
  const float* W_s = (const float*)d_in[20];
  const float* b_s = (const float*)d_in[21];
  const float* W_f = (const float*)d_in[22];
  const float* b_f = (const float*)d_in[23];
  const float* W_src = (const float*)d_in[24];
  const float* W_trg = (const float*)d_in[25];
  const float* W_o = (const float*)d_in[26];
  const float* b_o = (const float*)d_in[27];

  float* out = (float*)d_out;
  float* dx = out;
  float* dvec = out + (size_t)N_NODES * H;
  float* df = dvec + (size_t)N_NODES * L * H;

  // ---- workspace plan (~247 MB; offsets in f32 slots) ----
  float* ws = (float*)d_ws;
  __bf16* vecw = (__bf16*)ws;                 // NL*128 bf16
  __bf16* big = (__bf16*)(ws + 5120000);      // NL*640 bf16: [t12 256 | vec3 128 | vt 128 | vs 128]
  __bf16* fm = (__bf16*)(ws + 30720000);      // E*384 bf16: [dk 128 | dv 128 | dfw 128]
  __bf16* vm = (__bf16*)(ws + 43008000);      // E*128 bf16
  __bf16* s_buf = (__bf16*)(ws + 47104000);   // E*256 bf16
  float* qkv = ws + 55296000;                 // N*384 f32 (reused as o_buf)
  float* xln = ws + 59136000;                 // N*128 f32 (reused as x_agg)
  float* vdot = ws + 60416000;                // N*128 f32
  __bf16* Wt = (__bf16*)(ws + 61696000);      // [2048][128] bf16
  float* bqkv = ws + 61696000 + 131072;       // 384
  float* bfm = bqkv + 384;                    // 384
  int* rowptr = (int*)(bfm + 384);            // 10,001
  int* elist = rowptr + 10001;                // 64,000
  int* cnt = elist + 64000;                   // 10,000
  int* cursor = cnt + 10000;                  // 10,000

  float* o_buf = qkv;
  float* x_agg = xln;

  dim3 b256(256);

  // CSR build (depends only on ei)
  hipMemsetAsync(cnt, 0, N_NODES * sizeof(int), stream);
  hipMemsetAsync(cursor, 0, N_NODES * sizeof(int), stream);
  hist_kernel<<<dim3((N_EDGES + 255) / 256), b256, 0, stream>>>(ei, cnt);
  scan_kernel<<<dim3(1), dim3(1024), 0, stream>>>(cnt, rowptr);
  fill_kernel<<<dim3((N_EDGES + 255) / 256), b256, 0, stream>>>(ei, rowptr, cursor, elist);

  // 0. weight convert/transpose + bias concat
  wconv_kernel<<<dim3(258), b256, 0, stream>>>(W_vec, W_q, W_k, W_v, W_dk, W_dv, W_s, W_trg,
                                               W_src, W_f, W_o, b_q, b_k, b_v, b_dk, b_dv, b_f,
                                               Wt, bqkv, bfm);
  // 1. x_ln = layernorm(x)
  ln_kernel<<<dim3((N_NODES + 3) / 4), b256, 0, stream>>>(x, ln_g, ln_b, xln, N_NODES);
  // 2. vecw = vec * vln_w (bf16)
  vecw_kernel<<<dim3(2048), b256, 0, stream>>>(vec, vln_w, vecw, (size_t)NL * H / 8);
  // 3. big = vecw @ [Wvec | Wtrg | Wsrc]  (merged: t12|vec3|vt|vs; M=80000 %128==0)
  gemm_v2<__bf16, __bf16><<<dim3(625), b256, 0, stream>>>(vecw, Wt, nullptr, big, NL, 640, 640, 0);
  // 4. vec_dot
  vecdot_kernel<<<dim3(5000), b256, 0, stream>>>(big, vdot, N_NODES);
  // 5. qkv = xln @ [Wq|Wk|Wv] + b (f32 out)
  gemm_v2<float, float><<<dim3(79), b256, 0, stream>>>(xln, Wt + (size_t)640 * 128, bqkv, qkv,
                                                       N_NODES, 384, 384, 0);
  // 6. fm = silu(f_ij @ [Wdk|Wdv|Wf] + b) (merged dkdv|dfw)
  gemm_v2<float, __bf16><<<dim3(500), b256, 0, stream>>>(f_ij, Wt + (size_t)1024 * 128, bfm, fm,
                                                         N_EDGES, 384, 384, 1);
  // 7. message -> vm (bf16)
  msg_kernel<<<dim3(N_EDGES / 2), b256, 0, stream>>>(qkv, fm, r_ij, ei, vm);
  // 8. s = silu(vm @ W_s + b) (M=64000 %128==0)
  gemm_v2<__bf16, __bf16><<<dim3(500), b256, 0, stream>>>(vm, Wt + (size_t)1408 * 128, b_s, s_buf,
                                                          N_EDGES, 256, 256, 1);
  // 9. gather into x_agg and dvec (no atomics)
  gather_kernel<<<dim3(N_NODES / 2), b256, 0, stream>>>(vm, s_buf, vecw, d_ij, ei, rowptr,
                                                        elist, x_agg, dvec);
  // 10. edge update -> df (reads big vt/vs + fm dfw)
  edgeupd_kernel<<<dim3(N_EDGES / 2), b256, 0, stream>>>(big, d_ij, fm, ei, df);
  // 11. o = x_agg @ W_o + b (f32; overwrites qkv: consumed in 7)
  gemm_v2<float, float><<<dim3(79), b256, 0, stream>>>(x_agg, Wt + (size_t)1664 * 128, b_o, o_buf,
                                                       N_NODES, 384, 384, 0);
  // 12. final: dx, dvec += vec3*o1
  final_kernel<<<dim3(5000), b256, 0, stream>>>(o_buf, vdot, big, dx, dvec, N_NODES);
}

// Round 6
// 460.139 us; speedup vs baseline: 1.0724x; 1.0724x over previous
//
#include <hip/hip_runtime.h>
#include <hip/hip_bf16.h>
#include <math.h>

#define N_NODES 10000
#define N_EDGES 64000
#define H 128
#define L 8
#define NL (N_NODES * L)

typedef __attribute__((ext_vector_type(4))) float f32x4;
typedef __attribute__((ext_vector_type(8))) __bf16 bf16x8;

__device__ __forceinline__ float silu_f(float x) { return x / (1.f + __expf(-x)); }

// ---------------- LayerNorm: one wave per node ----------------
__global__ __launch_bounds__(256) void ln_kernel(const float* __restrict__ x,
                                                 const float* __restrict__ g,
                                                 const float* __restrict__ b,
                                                 float* __restrict__ out, int n_nodes) {
  int wave = threadIdx.x >> 6;
  int lane = threadIdx.x & 63;
  int n = blockIdx.x * 4 + wave;
  if (n >= n_nodes) return;
  const float* xr = x + (size_t)n * H;
  float a0 = xr[lane], a1 = xr[lane + 64];
  float s = a0 + a1;
#pragma unroll
  for (int off = 32; off >= 1; off >>= 1) s += __shfl_xor(s, off, 64);
  float mu = s * (1.f / H);
  float d0 = a0 - mu, d1 = a1 - mu;
  float v = d0 * d0 + d1 * d1;
#pragma unroll
  for (int off = 32; off >= 1; off >>= 1) v += __shfl_xor(v, off, 64);
  float rstd = rsqrtf(v * (1.f / H) + 1e-5f);
  float* orow = out + (size_t)n * H;
  orow[lane] = d0 * rstd * g[lane] + b[lane];
  orow[lane + 64] = d1 * rstd * g[lane + 64] + b[lane + 64];
}

// ---------------- vecw = vec * vln_w  -> bf16 ----------------
__global__ __launch_bounds__(256) void vecw_kernel(const float* __restrict__ vec,
                                                   const float* __restrict__ w,
                                                   __bf16* __restrict__ out, size_t total8) {
  size_t i = (size_t)blockIdx.x * blockDim.x + threadIdx.x;
  size_t stride = (size_t)gridDim.x * blockDim.x;
  for (; i < total8; i += stride) {
    size_t base = i * 8;
    f32x4 a = *(const f32x4*)(vec + base);
    f32x4 b = *(const f32x4*)(vec + base + 4);
    int c = (int)(base & 127);
    bf16x8 h;
    h[0] = (__bf16)(a[0] * w[c + 0]); h[1] = (__bf16)(a[1] * w[c + 1]);
    h[2] = (__bf16)(a[2] * w[c + 2]); h[3] = (__bf16)(a[3] * w[c + 3]);
    h[4] = (__bf16)(b[0] * w[c + 4]); h[5] = (__bf16)(b[1] * w[c + 5]);
    h[6] = (__bf16)(b[2] * w[c + 6]); h[7] = (__bf16)(b[3] * w[c + 7]);
    *(bf16x8*)(out + base) = h;
  }
}

// ---------------- weight convert into one [2048][128] bf16 table ----------------
// col map: [0,384) Wvec | [384,512) Wtrg | [512,640) Wsrc | [640,768) Wq | [768,896) Wk
//          | [896,1024) Wv | [1024,1152) Wdk | [1152,1280) Wdv | [1280,1408) Wf
//          | [1408,1664) Ws | [1664,2048) Wo
__global__ __launch_bounds__(256) void wconv_kernel(
    const float* __restrict__ Wvec, const float* __restrict__ Wq, const float* __restrict__ Wk,
    const float* __restrict__ Wv, const float* __restrict__ Wdk, const float* __restrict__ Wdv,
    const float* __restrict__ Ws, const float* __restrict__ Wtrg, const float* __restrict__ Wsrc,
    const float* __restrict__ Wf, const float* __restrict__ Wo,
    const float* __restrict__ bq, const float* __restrict__ bk, const float* __restrict__ bv,
    const float* __restrict__ bdk, const float* __restrict__ bdv, const float* __restrict__ bf,
    __bf16* __restrict__ Wt, float* __restrict__ bqkv, float* __restrict__ bfm) {
  int bid = blockIdx.x;
  int t = threadIdx.x;
  if (bid >= 256) {
    if (bid == 256) {
      if (t < 128) { bqkv[t] = bq[t]; bqkv[128 + t] = bk[t]; bqkv[256 + t] = bv[t]; }
    } else {
      if (t < 128) { bfm[t] = bdk[t]; bfm[128 + t] = bdv[t]; bfm[256 + t] = bf[t]; }
    }
    return;
  }
  int ct = bid >> 2, kt = bid & 3;
  int gc0 = ct * 32;
  const float* W; int ldw, sc0;
  if      (gc0 < 384)  { W = Wvec; ldw = 384; sc0 = gc0; }
  else if (gc0 < 512)  { W = Wtrg; ldw = 128; sc0 = gc0 - 384; }
  else if (gc0 < 640)  { W = Wsrc; ldw = 128; sc0 = gc0 - 512; }
  else if (gc0 < 768)  { W = Wq;   ldw = 128; sc0 = gc0 - 640; }
  else if (gc0 < 896)  { W = Wk;   ldw = 128; sc0 = gc0 - 768; }
  else if (gc0 < 1024) { W = Wv;   ldw = 128; sc0 = gc0 - 896; }
  else if (gc0 < 1152) { W = Wdk;  ldw = 128; sc0 = gc0 - 1024; }
  else if (gc0 < 1280) { W = Wdv;  ldw = 128; sc0 = gc0 - 1152; }
  else if (gc0 < 1408) { W = Wf;   ldw = 128; sc0 = gc0 - 1280; }
  else if (gc0 < 1664) { W = Ws;   ldw = 256; sc0 = gc0 - 1408; }
  else                 { W = Wo;   ldw = 384; sc0 = gc0 - 1664; }
  __shared__ float tile[32][33];
  int tx = t & 31, ty = t >> 5;
#pragma unroll
  for (int i = 0; i < 4; ++i)
    tile[ty + i * 8][tx] = W[(size_t)(kt * 32 + ty + i * 8) * ldw + sc0 + tx];
  __syncthreads();
#pragma unroll
  for (int i = 0; i < 4; ++i)
    Wt[(size_t)(gc0 + ty + i * 8) * 128 + kt * 32 + tx] = (__bf16)tile[tx][ty + i * 8];
}

// ---------------- MFMA GEMM v3: C[M,Nn] = act(A[M,128] @ Bt^T + bias) ----------------
// As-only LDS (32KB, swizzled); B hoisted per-ct into regs (one vmcnt batch); no inner barriers.
// FUSE: ct0*ct1 products reduced over L -> vdot; store only ct>=2 at col (ct-2)*128.
template <typename AT, typename CT, bool FUSE>
__global__ __launch_bounds__(256, 2) void gemm_v3(const AT* __restrict__ A,
                                                  const __bf16* __restrict__ Bt,
                                                  const float* __restrict__ bias,
                                                  CT* __restrict__ C,
                                                  float* __restrict__ vdot, int M, int Nn,
                                                  int ldc, int act) {
  __shared__ __bf16 As[128 * 128];
  const int tid = threadIdx.x;
  const int lane = tid & 63;
  const int wave = tid >> 6;
  const int wm = wave >> 1, wn = wave & 1;
  const int row0 = blockIdx.x * 128;

  if constexpr (sizeof(AT) == 2) {
#pragma unroll
    for (int i = 0; i < 8; ++i) {
      int c = tid + i * 256;  // 16B chunk; LDS dest linear
      int row = c >> 4, k8 = c & 15;
      int k8s = k8 ^ (row & 7);  // inverse-swizzled source == read-side XOR
      const AT* src = A + (size_t)(row0 + row) * 128 + k8s * 8;
      __builtin_amdgcn_global_load_lds((const __attribute__((address_space(1))) void*)src,
                                       (__attribute__((address_space(3))) void*)(As + c * 8),
                                       16, 0, 0);
    }
  } else {
#pragma unroll
    for (int i = 0; i < 8; ++i) {
      int c = tid + i * 256;
      int row = c >> 4, k8 = c & 15;
      int gm = row0 + row;
      bf16x8 h = {};
      if (gm < M) {
        f32x4 f0 = *(const f32x4*)(A + (size_t)gm * 128 + k8 * 8);
        f32x4 f1 = *(const f32x4*)(A + (size_t)gm * 128 + k8 * 8 + 4);
        h[0] = (__bf16)f0[0]; h[1] = (__bf16)f0[1]; h[2] = (__bf16)f0[2]; h[3] = (__bf16)f0[3];
        h[4] = (__bf16)f1[0]; h[5] = (__bf16)f1[1]; h[6] = (__bf16)f1[2]; h[7] = (__bf16)f1[3];
      }
      int byte = (c * 16) ^ ((row & 7) << 4);
      *(bf16x8*)((char*)As + byte) = h;
    }
  }
  __syncthreads();

  f32x4 pacc[4][4];  // FUSE: ct=0 accumulators
  const int ncTiles = Nn >> 7;
  for (int ct = 0; ct < ncTiles; ++ct) {
    // hoist all 16 B fragments for this ct (one wait, L2-hot weights)
    const __bf16* Bbase =
        Bt + ((size_t)(ct * 128 + wn * 64 + (lane & 15)) << 7) + ((lane >> 4) << 3);
    bf16x8 b[4][4];
#pragma unroll
    for (int ks = 0; ks < 4; ++ks)
#pragma unroll
      for (int ni = 0; ni < 4; ++ni)
        b[ks][ni] = *(const bf16x8*)(Bbase + (ni << 11) + (ks << 5));

    f32x4 acc[4][4];
#pragma unroll
    for (int mi = 0; mi < 4; ++mi)
#pragma unroll
      for (int ni = 0; ni < 4; ++ni) acc[mi][ni] = f32x4{0.f, 0.f, 0.f, 0.f};

#pragma unroll
    for (int ks = 0; ks < 4; ++ks) {
      bf16x8 a[4];
#pragma unroll
      for (int mi = 0; mi < 4; ++mi) {
        int row = wm * 64 + mi * 16 + (lane & 15);
        int byte = (row * 256 + ks * 64 + ((lane >> 4) << 4)) ^ ((row & 7) << 4);
        a[mi] = *(const bf16x8*)((const char*)As + byte);
      }
#pragma unroll
      for (int mi = 0; mi < 4; ++mi)
#pragma unroll
        for (int ni = 0; ni < 4; ++ni)
          acc[mi][ni] =
              __builtin_amdgcn_mfma_f32_16x16x32_bf16(a[mi], b[ks][ni], acc[mi][ni], 0, 0, 0);
    }

    if constexpr (FUSE) {
      if (ct == 0) {
#pragma unroll
        for (int mi = 0; mi < 4; ++mi)
#pragma unroll
          for (int ni = 0; ni < 4; ++ni) pacc[mi][ni] = acc[mi][ni];
        continue;
      }
      if (ct == 1) {
        // vdot[node][c] = sum over 8 L-rows of vec1*vec2
#pragma unroll
        for (int mi = 0; mi < 4; ++mi) {
#pragma unroll
          for (int ni = 0; ni < 4; ++ni) {
            float sr = pacc[mi][ni][0] * acc[mi][ni][0] + pacc[mi][ni][1] * acc[mi][ni][1] +
                       pacc[mi][ni][2] * acc[mi][ni][2] + pacc[mi][ni][3] * acc[mi][ni][3];
            sr += __shfl_xor(sr, 16, 64);
            if ((lane & 16) == 0) {
              int node = (row0 >> 3) + wm * 8 + mi * 2 + (lane >> 5);
              int col = wn * 64 + ni * 16 + (lane & 15);
              vdot[(size_t)node * 128 + col] = sr;
            }
          }
        }
        continue;
      }
    }

    int cstore = FUSE ? (ct - 2) * 128 : ct * 128;
#pragma unroll
    for (int mi = 0; mi < 4; ++mi) {
      int rbase = row0 + wm * 64 + mi * 16 + ((lane >> 4) << 2);
#pragma unroll
      for (int ni = 0; ni < 4; ++ni) {
        int gcol = cstore + wn * 64 + ni * 16 + (lane & 15);
        float bv = bias ? bias[ct * 128 + wn * 64 + ni * 16 + (lane & 15)] : 0.f;
#pragma unroll
        for (int r = 0; r < 4; ++r) {
          int grow = rbase + r;
          if (grow < M) {
            float xv = acc[mi][ni][r] + bv;
            if (act) xv = silu_f(xv);
            C[(size_t)grow * ldc + gcol] = (CT)xv;
          }
        }
      }
    }
  }
}

// ---------------- message: attn + vm per edge (dk/dv = fm cols 0..255, stride 384) ----------------
__global__ __launch_bounds__(256) void msg_kernel(const float* __restrict__ qkv,
                                                  const __bf16* __restrict__ fm,
                                                  const float* __restrict__ r_ij,
                                                  const int* __restrict__ ei,
                                                  __bf16* __restrict__ vm) {
  int e = blockIdx.x * 2 + (threadIdx.x >> 7);
  int h = threadIdx.x & 127;
  int src = ei[e], dst = ei[N_EDGES + e];
  float qv = qkv[(size_t)dst * 384 + h];
  float kv = qkv[(size_t)src * 384 + 128 + h];
  float vv = qkv[(size_t)src * 384 + 256 + h];
  float t = qv * kv * (float)fm[(size_t)e * 384 + h];
#pragma unroll
  for (int off = 8; off >= 1; off >>= 1) t += __shfl_xor(t, off, 16);
  float r = r_ij[e];
  float cut = 0.5f * (__cosf(0.6283185307f * r) + 1.f);
  cut = (r < 5.f) ? cut : 0.f;
  float attn = silu_f(t) * cut;
  vm[(size_t)e * H + h] = (__bf16)(vv * (float)fm[(size_t)e * 384 + 128 + h] * attn);
}

// ---------------- CSR build: histogram, scan, fill ----------------
__global__ __launch_bounds__(256) void hist_kernel(const int* __restrict__ ei,
                                                   int* __restrict__ cnt) {
  int e = blockIdx.x * 256 + threadIdx.x;
  if (e < N_EDGES) atomicAdd(&cnt[ei[N_EDGES + e]], 1);
}

__global__ __launch_bounds__(1024) void scan_kernel(const int* __restrict__ cnt,
                                                    int* __restrict__ rowptr) {
  __shared__ int wsum[16];
  int t = threadIdx.x;
  int base = t * 10;
  int local[10];
  int s = 0;
#pragma unroll
  for (int i = 0; i < 10; ++i) {
    int v = (base + i < N_NODES) ? cnt[base + i] : 0;
    local[i] = s;
    s += v;
  }
  int lane = t & 63, wave = t >> 6;
  int inc = s;
#pragma unroll
  for (int off = 1; off < 64; off <<= 1) {
    int u = __shfl_up(inc, off, 64);
    if (lane >= off) inc += u;
  }
  if (lane == 63) wsum[wave] = inc;
  __syncthreads();
  if (t == 0) {
    int acc = 0;
#pragma unroll
    for (int w = 0; w < 16; ++w) { int v = wsum[w]; wsum[w] = acc; acc += v; }
  }
  __syncthreads();
  int excl = inc - s + wsum[wave];
#pragma unroll
  for (int i = 0; i < 10; ++i)
    if (base + i <= N_NODES) rowptr[base + i] = excl + local[i];
}

__global__ __launch_bounds__(256) void fill_kernel(const int* __restrict__ ei,
                                                   const int* __restrict__ rowptr,
                                                   int* __restrict__ cursor,
                                                   int* __restrict__ elist) {
  int e = blockIdx.x * 256 + threadIdx.x;
  if (e < N_EDGES) {
    int d = ei[N_EDGES + e];
    int p = atomicAdd(&cursor[d], 1);
    elist[rowptr[d] + p] = e;
  }
}

// ---------------- gather: x_agg = Σ vm ; dvec = Σ vec_m (no atomics) ----------------
__global__ __launch_bounds__(256) void gather_kernel(const __bf16* __restrict__ vm,
                                                     const __bf16* __restrict__ s,
                                                     const __bf16* __restrict__ vecw,
                                                     const float* __restrict__ d_ij,
                                                     const int* __restrict__ ei,
                                                     const int* __restrict__ rowptr,
                                                     const int* __restrict__ elist,
                                                     float* __restrict__ x_agg,
                                                     float* __restrict__ dvec) {
  int n = blockIdx.x * 2 + (threadIdx.x >> 7);
  int h = threadIdx.x & 127;
  if (n >= N_NODES) return;
  int beg = rowptr[n], end = rowptr[n + 1];
  float ax = 0.f;
  float av[L] = {};
  for (int p = beg; p < end; ++p) {
    int e = elist[p];
    int src = ei[e];
    ax += (float)vm[(size_t)e * H + h];
    float s1 = (float)s[(size_t)e * 256 + h];
    float s2 = (float)s[(size_t)e * 256 + 128 + h];
    const __bf16* vrow = vecw + (size_t)src * L * H + h;
    const float* dd = d_ij + (size_t)e * L;
#pragma unroll
    for (int l = 0; l < L; l++) av[l] += (float)vrow[l * H] * s1 + s2 * dd[l];
  }
  x_agg[(size_t)n * H + h] = ax;
  float* drow = dvec + (size_t)n * L * H + h;
#pragma unroll
  for (int l = 0; l < L; l++) drow[l * H] = av[l];
}

// ---------------- edge update (big [NL][384]: vec3 @0, vt @128, vs @256; dfw = fm @256) ----------------
__global__ __launch_bounds__(256) void edgeupd_kernel(const __bf16* __restrict__ big,
                                                      const float* __restrict__ d_ij,
                                                      const __bf16* __restrict__ fm,
                                                      const int* __restrict__ ei,
                                                      float* __restrict__ df) {
  int e = blockIdx.x * 2 + (threadIdx.x >> 7);
  int h = threadIdx.x & 127;
  int src = ei[e], dst = ei[N_EDGES + e];
  float d[L];
  float sd2 = 0.f;
#pragma unroll
  for (int l = 0; l < L; l++) {
    d[l] = d_ij[(size_t)e * L + l];
    sd2 += d[l] * d[l];
  }
  const __bf16* arow = big + (size_t)dst * 8 * 384 + 128 + h;
  const __bf16* brow = big + (size_t)src * 8 * 384 + 256 + h;
  float dot = 0.f, p1 = 0.f, p2 = 0.f;
#pragma unroll
  for (int l = 0; l < L; l++) {
    float a = (float)arow[l * 384], bb = (float)brow[l * 384];
    dot += a * bb;
    p1 += a * d[l];
    p2 += bb * d[l];
  }
  float wdot = dot - p1 * p2 * (2.f - sd2);
  df[(size_t)e * H + h] = (float)fm[(size_t)e * 384 + 256 + h] * wdot;
}

// ---------------- final node update (vec3 = big cols 0..127) ----------------
__global__ __launch_bounds__(256) void final_kernel(const float* __restrict__ o,
                                                    const float* __restrict__ vdot,
                                                    const __bf16* __restrict__ big,
                                                    float* __restrict__ dx,
                                                    float* __restrict__ dvec, int n_nodes) {
  int n = blockIdx.x * 2 + (threadIdx.x >> 7);
  int h = threadIdx.x & 127;
  if (n >= n_nodes) return;
  float o1 = o[(size_t)n * 384 + h];
  float o2 = o[(size_t)n * 384 + 128 + h];
  float o3 = o[(size_t)n * 384 + 256 + h];
  dx[(size_t)n * H + h] = vdot[(size_t)n * H + h] * o2 + o3;
  float* drow = dvec + (size_t)n * L * H + h;
  const __bf16* v3 = big + (size_t)n * 8 * 384 + h;
#pragma unroll
  for (int l = 0; l < L; l++) drow[l * H] += (float)v3[l * 384] * o1;
}

extern "C" void kernel_launch(void* const* d_in, const int* in_sizes, int n_in, void* d_out,
                              int out_size, void* d_ws, size_t ws_size, hipStream_t stream) {
  const float* x = (const float*)d_in[0];
  const float* vec = (const float*)d_in[1];
  const float* f_ij = (const float*)d_in[2];
  const float* d_ij = (const float*)d_in[3];
  const float* r_ij = (const float*)d_in[4];
  const int* ei = (const int*)d_in[5];
  const float* ln_g = (const float*)d_in[6];
  const float* ln_b = (const float*)d_in[7];
  const float* vln_w = (const float*)d_in[8];
  const float* W_vec = (const float*)d_in[9];
  const float* W_q = (const float*)d_in[10];
  const float* b_q = (const float*)d_in[11];
  const float* W_k = (const float*)d_in[12];
  const float* b_k = (const float*)d_in[13];
  const float* W_v = (const float*)d_in[14];
  const float* b_v = (const float*)d_in[15];
  const float* W_dk = (const float*)d_in[16];
  const float* b_dk = (const float*)d_in[17];
  const float* W_dv = (const float*)d_in[18];
  const float* b_dv = (const float*)d_in[19];
  const float* W_s = (const float*)d_in[20];
  const float* b_s = (const float*)d_in[21];
  const float* W_f = (const float*)d_in[22];
  const float* b_f = (const float*)d_in[23];
  const float* W_src = (const float*)d_in[24];
  const float* W_trg = (const float*)d_in[25];
  const float* W_o = (const float*)d_in[26];
  const float* b_o = (const float*)d_in[27];

  float* out = (float*)d_out;
  float* dx = out;
  float* dvec = out + (size_t)N_NODES * H;
  float* df = dvec + (size_t)N_NODES * L * H;

  // ---- workspace plan (~207 MB; offsets in f32 slots) ----
  float* ws = (float*)d_ws;
  __bf16* vecw = (__bf16*)ws;                 // NL*128 bf16
  __bf16* big = (__bf16*)(ws + 5120000);      // NL*384 bf16: [vec3 128 | vt 128 | vs 128]
  __bf16* fm = (__bf16*)(ws + 20480000);      // E*384 bf16: [dk | dv | dfw]
  __bf16* vm = (__bf16*)(ws + 32768000);      // E*128 bf16
  __bf16* s_buf = (__bf16*)(ws + 36864000);   // E*256 bf16
  float* qkv = ws + 45056000;                 // N*384 f32 (reused as o_buf)
  float* xln = ws + 48896000;                 // N*128 f32 (reused as x_agg)
  float* vdot = ws + 50176000;                // N*128 f32
  __bf16* Wt = (__bf16*)(ws + 51456000);      // [2048][128] bf16
  float* bqkv = ws + 51456000 + 131072;       // 384
  float* bfm = bqkv + 384;                    // 384
  int* rowptr = (int*)(bfm + 384);            // 10,001
  int* elist = rowptr + 10001;                // 64,000
  int* cnt = elist + 64000;                   // 10,000
  int* cursor = cnt + 10000;                  // 10,000

  float* o_buf = qkv;
  float* x_agg = xln;

  dim3 b256(256);

  // CSR build (depends only on ei)
  hipMemsetAsync(cnt, 0, N_NODES * sizeof(int), stream);
  hipMemsetAsync(cursor, 0, N_NODES * sizeof(int), stream);
  hist_kernel<<<dim3((N_EDGES + 255) / 256), b256, 0, stream>>>(ei, cnt);
  scan_kernel<<<dim3(1), dim3(1024), 0, stream>>>(cnt, rowptr);
  fill_kernel<<<dim3((N_EDGES + 255) / 256), b256, 0, stream>>>(ei, rowptr, cursor, elist);

  // 0. weight convert/transpose + bias concat
  wconv_kernel<<<dim3(258), b256, 0, stream>>>(W_vec, W_q, W_k, W_v, W_dk, W_dv, W_s, W_trg,
                                               W_src, W_f, W_o, b_q, b_k, b_v, b_dk, b_dv, b_f,
                                               Wt, bqkv, bfm);
  // 1. x_ln = layernorm(x)
  ln_kernel<<<dim3((N_NODES + 3) / 4), b256, 0, stream>>>(x, ln_g, ln_b, xln, N_NODES);
  // 2. vecw = vec * vln_w (bf16)
  vecw_kernel<<<dim3(2048), b256, 0, stream>>>(vec, vln_w, vecw, (size_t)NL * H / 8);
  // 3. big = vecw @ [Wvec|Wtrg|Wsrc], vec_dot fused (t12 never materialized)
  gemm_v3<__bf16, __bf16, true><<<dim3(625), b256, 0, stream>>>(vecw, Wt, nullptr, big, vdot,
                                                                NL, 640, 384, 0);
  // 4. qkv = xln @ [Wq|Wk|Wv] + b (f32 out)
  gemm_v3<float, float, false><<<dim3(79), b256, 0, stream>>>(xln, Wt + (size_t)640 * 128, bqkv,
                                                              qkv, nullptr, N_NODES, 384, 384, 0);
  // 5. fm = silu(f_ij @ [Wdk|Wdv|Wf] + b)
  gemm_v3<float, __bf16, false><<<dim3(500), b256, 0, stream>>>(f_ij, Wt + (size_t)1024 * 128,
                                                                bfm, fm, nullptr, N_EDGES, 384,
                                                                384, 1);
  // 6. message -> vm (bf16)
  msg_kernel<<<dim3(N_EDGES / 2), b256, 0, stream>>>(qkv, fm, r_ij, ei, vm);
  // 7. s = silu(vm @ W_s + b)
  gemm_v3<__bf16, __bf16, false><<<dim3(500), b256, 0, stream>>>(vm, Wt + (size_t)1408 * 128,
                                                                 b_s, s_buf, nullptr, N_EDGES,
                                                                 256, 256, 1);
  // 8. gather into x_agg and dvec (no atomics)
  gather_kernel<<<dim3(N_NODES / 2), b256, 0, stream>>>(vm, s_buf, vecw, d_ij, ei, rowptr,
                                                        elist, x_agg, dvec);
  // 9. edge update -> df (reads big vt/vs + fm dfw)
  edgeupd_kernel<<<dim3(N_EDGES / 2), b256, 0, stream>>>(big, d_ij, fm, ei, df);
  // 10. o = x_agg @ W_o + b (f32; overwrites qkv: consumed in 6)
  gemm_v3<float, float, false><<<dim3(79), b256, 0, stream>>>(x_agg, Wt + (size_t)1664 * 128,
                                                              b_o, o_buf, nullptr, N_NODES, 384,
                                                              384, 0);
  // 11. final: dx, dvec += vec3*o1
  final_kernel<<<dim3(5000), b256, 0, stream>>>(o_buf, vdot, big, dx, dvec, N_NODES);
}

// Round 7
// 378.836 us; speedup vs baseline: 1.3025x; 1.2146x over previous
//
#include <hip/hip_runtime.h>
#include <hip/hip_bf16.h>
#include <math.h>

#define N_NODES 10000
#define N_EDGES 64000
#define H 128
#define L 8
#define NL (N_NODES * L)

typedef __attribute__((ext_vector_type(4))) float f32x4;
typedef __attribute__((ext_vector_type(8))) __bf16 bf16x8;

__device__ __forceinline__ float silu_f(float x) { return x / (1.f + __expf(-x)); }

// ---------------- LayerNorm: one wave per node ----------------
__global__ __launch_bounds__(256) void ln_kernel(const float* __restrict__ x,
                                                 const float* __restrict__ g,
                                                 const float* __restrict__ b,
                                                 float* __restrict__ out, int n_nodes) {
  int wave = threadIdx.x >> 6;
  int lane = threadIdx.x & 63;
  int n = blockIdx.x * 4 + wave;
  if (n >= n_nodes) return;
  const float* xr = x + (size_t)n * H;
  float a0 = xr[lane], a1 = xr[lane + 64];
  float s = a0 + a1;
#pragma unroll
  for (int off = 32; off >= 1; off >>= 1) s += __shfl_xor(s, off, 64);
  float mu = s * (1.f / H);
  float d0 = a0 - mu, d1 = a1 - mu;
  float v = d0 * d0 + d1 * d1;
#pragma unroll
  for (int off = 32; off >= 1; off >>= 1) v += __shfl_xor(v, off, 64);
  float rstd = rsqrtf(v * (1.f / H) + 1e-5f);
  float* orow = out + (size_t)n * H;
  orow[lane] = d0 * rstd * g[lane] + b[lane];
  orow[lane + 64] = d1 * rstd * g[lane + 64] + b[lane + 64];
}

// ---------------- vecw = vec * vln_w  -> bf16 ----------------
__global__ __launch_bounds__(256) void vecw_kernel(const float* __restrict__ vec,
                                                   const float* __restrict__ w,
                                                   __bf16* __restrict__ out, size_t total8) {
  size_t i = (size_t)blockIdx.x * blockDim.x + threadIdx.x;
  size_t stride = (size_t)gridDim.x * blockDim.x;
  for (; i < total8; i += stride) {
    size_t base = i * 8;
    f32x4 a = *(const f32x4*)(vec + base);
    f32x4 b = *(const f32x4*)(vec + base + 4);
    int c = (int)(base & 127);
    bf16x8 h;
    h[0] = (__bf16)(a[0] * w[c + 0]); h[1] = (__bf16)(a[1] * w[c + 1]);
    h[2] = (__bf16)(a[2] * w[c + 2]); h[3] = (__bf16)(a[3] * w[c + 3]);
    h[4] = (__bf16)(b[0] * w[c + 4]); h[5] = (__bf16)(b[1] * w[c + 5]);
    h[6] = (__bf16)(b[2] * w[c + 6]); h[7] = (__bf16)(b[3] * w[c + 7]);
    *(bf16x8*)(out + base) = h;
  }
}

// ---------------- weight convert into one [2048][128] bf16 table ----------------
// col map: [0,384) Wvec | [384,512) Wtrg | [512,640) Wsrc | [640,768) Wq | [768,896) Wk
//          | [896,1024) Wv | [1024,1152) Wdk | [1152,1280) Wdv | [1280,1408) Wf
//          | [1408,1664) Ws | [1664,2048) Wo
__global__ __launch_bounds__(256) void wconv_kernel(
    const float* __restrict__ Wvec, const float* __restrict__ Wq, const float* __restrict__ Wk,
    const float* __restrict__ Wv, const float* __restrict__ Wdk, const float* __restrict__ Wdv,
    const float* __restrict__ Ws, const float* __restrict__ Wtrg, const float* __restrict__ Wsrc,
    const float* __restrict__ Wf, const float* __restrict__ Wo,
    const float* __restrict__ bq, const float* __restrict__ bk, const float* __restrict__ bv,
    const float* __restrict__ bdk, const float* __restrict__ bdv, const float* __restrict__ bf,
    __bf16* __restrict__ Wt, float* __restrict__ bqkv, float* __restrict__ bfm) {
  int bid = blockIdx.x;
  int t = threadIdx.x;
  if (bid >= 256) {
    if (bid == 256) {
      if (t < 128) { bqkv[t] = bq[t]; bqkv[128 + t] = bk[t]; bqkv[256 + t] = bv[t]; }
    } else {
      if (t < 128) { bfm[t] = bdk[t]; bfm[128 + t] = bdv[t]; bfm[256 + t] = bf[t]; }
    }
    return;
  }
  int ct = bid >> 2, kt = bid & 3;
  int gc0 = ct * 32;
  const float* W; int ldw, sc0;
  if      (gc0 < 384)  { W = Wvec; ldw = 384; sc0 = gc0; }
  else if (gc0 < 512)  { W = Wtrg; ldw = 128; sc0 = gc0 - 384; }
  else if (gc0 < 640)  { W = Wsrc; ldw = 128; sc0 = gc0 - 512; }
  else if (gc0 < 768)  { W = Wq;   ldw = 128; sc0 = gc0 - 640; }
  else if (gc0 < 896)  { W = Wk;   ldw = 128; sc0 = gc0 - 768; }
  else if (gc0 < 1024) { W = Wv;   ldw = 128; sc0 = gc0 - 896; }
  else if (gc0 < 1152) { W = Wdk;  ldw = 128; sc0 = gc0 - 1024; }
  else if (gc0 < 1280) { W = Wdv;  ldw = 128; sc0 = gc0 - 1152; }
  else if (gc0 < 1408) { W = Wf;   ldw = 128; sc0 = gc0 - 1280; }
  else if (gc0 < 1664) { W = Ws;   ldw = 256; sc0 = gc0 - 1408; }
  else                 { W = Wo;   ldw = 384; sc0 = gc0 - 1664; }
  __shared__ float tile[32][33];
  int tx = t & 31, ty = t >> 5;
#pragma unroll
  for (int i = 0; i < 4; ++i)
    tile[ty + i * 8][tx] = W[(size_t)(kt * 32 + ty + i * 8) * ldw + sc0 + tx];
  __syncthreads();
#pragma unroll
  for (int i = 0; i < 4; ++i)
    Wt[(size_t)(gc0 + ty + i * 8) * 128 + kt * 32 + tx] = (__bf16)tile[tx][ty + i * 8];
}

// ---------------- MFMA GEMM v4: 2D grid (M-tile, ct-tile); one 128x128 tile per block ----------
// As-only LDS (32KB, swizzled). FUSE: blockIdx.y==0 computes ct0,ct1 -> vdot only;
// y>=1 computes Bt-tile ct=y+1, stores at col (y-1)*128. Non-FUSE: ct=y, store col y*128.
template <typename AT, typename CT, bool FUSE>
__global__ __launch_bounds__(256, 3) void gemm_v4(const AT* __restrict__ A,
                                                  const __bf16* __restrict__ Bt,
                                                  const float* __restrict__ bias,
                                                  CT* __restrict__ C,
                                                  float* __restrict__ vdot, int M, int ldc,
                                                  int act) {
  __shared__ __bf16 As[128 * 128];
  const int tid = threadIdx.x;
  const int lane = tid & 63;
  const int wave = tid >> 6;
  const int wm = wave >> 1, wn = wave & 1;
  const int row0 = blockIdx.x * 128;

  if constexpr (sizeof(AT) == 2) {
#pragma unroll
    for (int i = 0; i < 8; ++i) {
      int c = tid + i * 256;  // 16B chunk; LDS dest linear
      int row = c >> 4, k8 = c & 15;
      int k8s = k8 ^ (row & 7);  // inverse-swizzled source == read-side XOR
      const AT* src = A + (size_t)(row0 + row) * 128 + k8s * 8;
      __builtin_amdgcn_global_load_lds((const __attribute__((address_space(1))) void*)src,
                                       (__attribute__((address_space(3))) void*)(As + c * 8),
                                       16, 0, 0);
    }
  } else {
#pragma unroll
    for (int i = 0; i < 8; ++i) {
      int c = tid + i * 256;
      int row = c >> 4, k8 = c & 15;
      int gm = row0 + row;
      bf16x8 h = {};
      if (gm < M) {
        f32x4 f0 = *(const f32x4*)(A + (size_t)gm * 128 + k8 * 8);
        f32x4 f1 = *(const f32x4*)(A + (size_t)gm * 128 + k8 * 8 + 4);
        h[0] = (__bf16)f0[0]; h[1] = (__bf16)f0[1]; h[2] = (__bf16)f0[2]; h[3] = (__bf16)f0[3];
        h[4] = (__bf16)f1[0]; h[5] = (__bf16)f1[1]; h[6] = (__bf16)f1[2]; h[7] = (__bf16)f1[3];
      }
      int byte = (c * 16) ^ ((row & 7) << 4);
      *(bf16x8*)((char*)As + byte) = h;
    }
  }
  __syncthreads();

  const int y = blockIdx.y;

  if constexpr (FUSE) {
    if (y == 0) {
      // ct=0 (vec1) and ct=1 (vec2) -> vdot; per-ks B loads (VGPR budget)
      f32x4 pacc[4][4], acc[4][4];
#pragma unroll
      for (int mi = 0; mi < 4; ++mi)
#pragma unroll
        for (int ni = 0; ni < 4; ++ni) {
          pacc[mi][ni] = f32x4{0.f, 0.f, 0.f, 0.f};
          acc[mi][ni] = f32x4{0.f, 0.f, 0.f, 0.f};
        }
#pragma unroll
      for (int ct = 0; ct < 2; ++ct) {
        const __bf16* Bbase =
            Bt + ((size_t)(ct * 128 + wn * 64 + (lane & 15)) << 7) + ((lane >> 4) << 3);
#pragma unroll
        for (int ks = 0; ks < 4; ++ks) {
          bf16x8 b[4];
#pragma unroll
          for (int ni = 0; ni < 4; ++ni) b[ni] = *(const bf16x8*)(Bbase + (ni << 11) + (ks << 5));
          bf16x8 a[4];
#pragma unroll
          for (int mi = 0; mi < 4; ++mi) {
            int row = wm * 64 + mi * 16 + (lane & 15);
            int byte = (row * 256 + ks * 64 + ((lane >> 4) << 4)) ^ ((row & 7) << 4);
            a[mi] = *(const bf16x8*)((const char*)As + byte);
          }
          if (ct == 0) {
#pragma unroll
            for (int mi = 0; mi < 4; ++mi)
#pragma unroll
              for (int ni = 0; ni < 4; ++ni)
                pacc[mi][ni] =
                    __builtin_amdgcn_mfma_f32_16x16x32_bf16(a[mi], b[ni], pacc[mi][ni], 0, 0, 0);
          } else {
#pragma unroll
            for (int mi = 0; mi < 4; ++mi)
#pragma unroll
              for (int ni = 0; ni < 4; ++ni)
                acc[mi][ni] =
                    __builtin_amdgcn_mfma_f32_16x16x32_bf16(a[mi], b[ni], acc[mi][ni], 0, 0, 0);
          }
        }
      }
      // vdot[node][c] = sum over 8 L-rows of vec1*vec2
#pragma unroll
      for (int mi = 0; mi < 4; ++mi) {
#pragma unroll
        for (int ni = 0; ni < 4; ++ni) {
          float sr = pacc[mi][ni][0] * acc[mi][ni][0] + pacc[mi][ni][1] * acc[mi][ni][1] +
                     pacc[mi][ni][2] * acc[mi][ni][2] + pacc[mi][ni][3] * acc[mi][ni][3];
          sr += __shfl_xor(sr, 16, 64);
          if ((lane & 16) == 0) {
            int node = (row0 >> 3) + wm * 8 + mi * 2 + (lane >> 5);
            int col = wn * 64 + ni * 16 + (lane & 15);
            vdot[(size_t)node * 128 + col] = sr;
          }
        }
      }
      return;
    }
  }

  const int ct = FUSE ? y + 1 : y;
  const int cstore = FUSE ? (y - 1) * 128 : y * 128;

  // hoist all 16 B fragments (one wait; weights L2-hot)
  const __bf16* Bbase =
      Bt + ((size_t)(ct * 128 + wn * 64 + (lane & 15)) << 7) + ((lane >> 4) << 3);
  bf16x8 b[4][4];
#pragma unroll
  for (int ks = 0; ks < 4; ++ks)
#pragma unroll
    for (int ni = 0; ni < 4; ++ni) b[ks][ni] = *(const bf16x8*)(Bbase + (ni << 11) + (ks << 5));

  f32x4 acc[4][4];
#pragma unroll
  for (int mi = 0; mi < 4; ++mi)
#pragma unroll
    for (int ni = 0; ni < 4; ++ni) acc[mi][ni] = f32x4{0.f, 0.f, 0.f, 0.f};

#pragma unroll
  for (int ks = 0; ks < 4; ++ks) {
    bf16x8 a[4];
#pragma unroll
    for (int mi = 0; mi < 4; ++mi) {
      int row = wm * 64 + mi * 16 + (lane & 15);
      int byte = (row * 256 + ks * 64 + ((lane >> 4) << 4)) ^ ((row & 7) << 4);
      a[mi] = *(const bf16x8*)((const char*)As + byte);
    }
#pragma unroll
    for (int mi = 0; mi < 4; ++mi)
#pragma unroll
      for (int ni = 0; ni < 4; ++ni)
        acc[mi][ni] =
            __builtin_amdgcn_mfma_f32_16x16x32_bf16(a[mi], b[ks][ni], acc[mi][ni], 0, 0, 0);
  }

#pragma unroll
  for (int mi = 0; mi < 4; ++mi) {
    int rbase = row0 + wm * 64 + mi * 16 + ((lane >> 4) << 2);
#pragma unroll
    for (int ni = 0; ni < 4; ++ni) {
      int gcol = cstore + wn * 64 + ni * 16 + (lane & 15);
      float bv = bias ? bias[ct * 128 + wn * 64 + ni * 16 + (lane & 15)] : 0.f;
#pragma unroll
      for (int r = 0; r < 4; ++r) {
        int grow = rbase + r;
        if (grow < M) {
          float xv = acc[mi][ni][r] + bv;
          if (act) xv = silu_f(xv);
          C[(size_t)grow * ldc + gcol] = (CT)xv;
        }
      }
    }
  }
}

// ---------------- message: attn + vm per edge (dk/dv = fm cols 0..255, stride 384) ----------------
__global__ __launch_bounds__(256) void msg_kernel(const float* __restrict__ qkv,
                                                  const __bf16* __restrict__ fm,
                                                  const float* __restrict__ r_ij,
                                                  const int* __restrict__ ei,
                                                  __bf16* __restrict__ vm) {
  int e = blockIdx.x * 2 + (threadIdx.x >> 7);
  int h = threadIdx.x & 127;
  int src = ei[e], dst = ei[N_EDGES + e];
  float qv = qkv[(size_t)dst * 384 + h];
  float kv = qkv[(size_t)src * 384 + 128 + h];
  float vv = qkv[(size_t)src * 384 + 256 + h];
  float t = qv * kv * (float)fm[(size_t)e * 384 + h];
#pragma unroll
  for (int off = 8; off >= 1; off >>= 1) t += __shfl_xor(t, off, 16);
  float r = r_ij[e];
  float cut = 0.5f * (__cosf(0.6283185307f * r) + 1.f);
  cut = (r < 5.f) ? cut : 0.f;
  float attn = silu_f(t) * cut;
  vm[(size_t)e * H + h] = (__bf16)(vv * (float)fm[(size_t)e * 384 + 128 + h] * attn);
}

// ---------------- CSR build: histogram, scan, fill ----------------
__global__ __launch_bounds__(256) void hist_kernel(const int* __restrict__ ei,
                                                   int* __restrict__ cnt) {
  int e = blockIdx.x * 256 + threadIdx.x;
  if (e < N_EDGES) atomicAdd(&cnt[ei[N_EDGES + e]], 1);
}

__global__ __launch_bounds__(1024) void scan_kernel(const int* __restrict__ cnt,
                                                    int* __restrict__ rowptr) {
  __shared__ int wsum[16];
  int t = threadIdx.x;
  int base = t * 10;
  int local[10];
  int s = 0;
#pragma unroll
  for (int i = 0; i < 10; ++i) {
    int v = (base + i < N_NODES) ? cnt[base + i] : 0;
    local[i] = s;
    s += v;
  }
  int lane = t & 63, wave = t >> 6;
  int inc = s;
#pragma unroll
  for (int off = 1; off < 64; off <<= 1) {
    int u = __shfl_up(inc, off, 64);
    if (lane >= off) inc += u;
  }
  if (lane == 63) wsum[wave] = inc;
  __syncthreads();
  if (t == 0) {
    int acc = 0;
#pragma unroll
    for (int w = 0; w < 16; ++w) { int v = wsum[w]; wsum[w] = acc; acc += v; }
  }
  __syncthreads();
  int excl = inc - s + wsum[wave];
#pragma unroll
  for (int i = 0; i < 10; ++i)
    if (base + i <= N_NODES) rowptr[base + i] = excl + local[i];
}

__global__ __launch_bounds__(256) void fill_kernel(const int* __restrict__ ei,
                                                   const int* __restrict__ rowptr,
                                                   int* __restrict__ cursor,
                                                   int* __restrict__ elist) {
  int e = blockIdx.x * 256 + threadIdx.x;
  if (e < N_EDGES) {
    int d = ei[N_EDGES + e];
    int p = atomicAdd(&cursor[d], 1);
    elist[rowptr[d] + p] = e;
  }
}

// ---------------- gather: x_agg = Σ vm ; dvec = Σ vec_m (no atomics) ----------------
__global__ __launch_bounds__(256) void gather_kernel(const __bf16* __restrict__ vm,
                                                     const __bf16* __restrict__ s,
                                                     const __bf16* __restrict__ vecw,
                                                     const float* __restrict__ d_ij,
                                                     const int* __restrict__ ei,
                                                     const int* __restrict__ rowptr,
                                                     const int* __restrict__ elist,
                                                     float* __restrict__ x_agg,
                                                     float* __restrict__ dvec) {
  int n = blockIdx.x * 2 + (threadIdx.x >> 7);
  int h = threadIdx.x & 127;
  if (n >= N_NODES) return;
  int beg = rowptr[n], end = rowptr[n + 1];
  float ax = 0.f;
  float av[L] = {};
  for (int p = beg; p < end; ++p) {
    int e = elist[p];
    int src = ei[e];
    ax += (float)vm[(size_t)e * H + h];
    float s1 = (float)s[(size_t)e * 256 + h];
    float s2 = (float)s[(size_t)e * 256 + 128 + h];
    const __bf16* vrow = vecw + (size_t)src * L * H + h;
    const float* dd = d_ij + (size_t)e * L;
#pragma unroll
    for (int l = 0; l < L; l++) av[l] += (float)vrow[l * H] * s1 + s2 * dd[l];
  }
  x_agg[(size_t)n * H + h] = ax;
  float* drow = dvec + (size_t)n * L * H + h;
#pragma unroll
  for (int l = 0; l < L; l++) drow[l * H] = av[l];
}

// ---------------- edge update (big [NL][384]: vec3 @0, vt @128, vs @256; dfw = fm @256) ----------------
__global__ __launch_bounds__(256) void edgeupd_kernel(const __bf16* __restrict__ big,
                                                      const float* __restrict__ d_ij,
                                                      const __bf16* __restrict__ fm,
                                                      const int* __restrict__ ei,
                                                      float* __restrict__ df) {
  int e = blockIdx.x * 2 + (threadIdx.x >> 7);
  int h = threadIdx.x & 127;
  int src = ei[e], dst = ei[N_EDGES + e];
  float d[L];
  float sd2 = 0.f;
#pragma unroll
  for (int l = 0; l < L; l++) {
    d[l] = d_ij[(size_t)e * L + l];
    sd2 += d[l] * d[l];
  }
  const __bf16* arow = big + (size_t)dst * 8 * 384 + 128 + h;
  const __bf16* brow = big + (size_t)src * 8 * 384 + 256 + h;
  float dot = 0.f, p1 = 0.f, p2 = 0.f;
#pragma unroll
  for (int l = 0; l < L; l++) {
    float a = (float)arow[l * 384], bb = (float)brow[l * 384];
    dot += a * bb;
    p1 += a * d[l];
    p2 += bb * d[l];
  }
  float wdot = dot - p1 * p2 * (2.f - sd2);
  df[(size_t)e * H + h] = (float)fm[(size_t)e * 384 + 256 + h] * wdot;
}

// ---------------- final node update (vec3 = big cols 0..127) ----------------
__global__ __launch_bounds__(256) void final_kernel(const float* __restrict__ o,
                                                    const float* __restrict__ vdot,
                                                    const __bf16* __restrict__ big,
                                                    float* __restrict__ dx,
                                                    float* __restrict__ dvec, int n_nodes) {
  int n = blockIdx.x * 2 + (threadIdx.x >> 7);
  int h = threadIdx.x & 127;
  if (n >= n_nodes) return;
  float o1 = o[(size_t)n * 384 + h];
  float o2 = o[(size_t)n * 384 + 128 + h];
  float o3 = o[(size_t)n * 384 + 256 + h];
  dx[(size_t)n * H + h] = vdot[(size_t)n * H + h] * o2 + o3;
  float* drow = dvec + (size_t)n * L * H + h;
  const __bf16* v3 = big + (size_t)n * 8 * 384 + h;
#pragma unroll
  for (int l = 0; l < L; l++) drow[l * H] += (float)v3[l * 384] * o1;
}

extern "C" void kernel_launch(void* const* d_in, const int* in_sizes, int n_in, void* d_out,
                              int out_size, void* d_ws, size_t ws_size, hipStream_t stream) {
  const float* x = (const float*)d_in[0];
  const float* vec = (const float*)d_in[1];
  const float* f_ij = (const float*)d_in[2];
  const float* d_ij = (const float*)d_in[3];
  const float* r_ij = (const float*)d_in[4];
  const int* ei = (const int*)d_in[5];
  const float* ln_g = (const float*)d_in[6];
  const float* ln_b = (const float*)d_in[7];
  const float* vln_w = (const float*)d_in[8];
  const float* W_vec = (const float*)d_in[9];
  const float* W_q = (const float*)d_in[10];
  const float* b_q = (const float*)d_in[11];
  const float* W_k = (const float*)d_in[12];
  const float* b_k = (const float*)d_in[13];
  const float* W_v = (const float*)d_in[14];
  const float* b_v = (const float*)d_in[15];
  const float* W_dk = (const float*)d_in[16];
  const float* b_dk = (const float*)d_in[17];
  const float* W_dv = (const float*)d_in[18];
  const float* b_dv = (const float*)d_in[19];
  const float* W_s = (const float*)d_in[20];
  const float* b_s = (const float*)d_in[21];
  const float* W_f = (const float*)d_in[22];
  const float* b_f = (const float*)d_in[23];
  const float* W_src = (const float*)d_in[24];
  const float* W_trg = (const float*)d_in[25];
  const float* W_o = (const float*)d_in[26];
  const float* b_o = (const float*)d_in[27];

  float* out = (float*)d_out;
  float* dx = out;
  float* dvec = out + (size_t)N_NODES * H;
  float* df = dvec + (size_t)N_NODES * L * H;

  // ---- workspace plan (~207 MB; offsets in f32 slots) ----
  float* ws = (float*)d_ws;
  __bf16* vecw = (__bf16*)ws;                 // NL*128 bf16
  __bf16* big = (__bf16*)(ws + 5120000);      // NL*384 bf16: [vec3 128 | vt 128 | vs 128]
  __bf16* fm = (__bf16*)(ws + 20480000);      // E*384 bf16: [dk | dv | dfw]
  __bf16* vm = (__bf16*)(ws + 32768000);      // E*128 bf16
  __bf16* s_buf = (__bf16*)(ws + 36864000);   // E*256 bf16
  float* qkv = ws + 45056000;                 // N*384 f32 (reused as o_buf)
  float* xln = ws + 48896000;                 // N*128 f32 (reused as x_agg)
  float* vdot = ws + 50176000;                // N*128 f32
  __bf16* Wt = (__bf16*)(ws + 51456000);      // [2048][128] bf16
  float* bqkv = ws + 51456000 + 131072;       // 384
  float* bfm = bqkv + 384;                    // 384
  int* rowptr = (int*)(bfm + 384);            // 10,001
  int* elist = rowptr + 10001;                // 64,000
  int* cnt = elist + 64000;                   // 10,000
  int* cursor = cnt + 10000;                  // 10,000

  float* o_buf = qkv;
  float* x_agg = xln;

  dim3 b256(256);

  // CSR build (depends only on ei)
  hipMemsetAsync(cnt, 0, N_NODES * sizeof(int), stream);
  hipMemsetAsync(cursor, 0, N_NODES * sizeof(int), stream);
  hist_kernel<<<dim3((N_EDGES + 255) / 256), b256, 0, stream>>>(ei, cnt);
  scan_kernel<<<dim3(1), dim3(1024), 0, stream>>>(cnt, rowptr);
  fill_kernel<<<dim3((N_EDGES + 255) / 256), b256, 0, stream>>>(ei, rowptr, cursor, elist);

  // 0. weight convert/transpose + bias concat
  wconv_kernel<<<dim3(258), b256, 0, stream>>>(W_vec, W_q, W_k, W_v, W_dk, W_dv, W_s, W_trg,
                                               W_src, W_f, W_o, b_q, b_k, b_v, b_dk, b_dv, b_f,
                                               Wt, bqkv, bfm);
  // 1. x_ln = layernorm(x)
  ln_kernel<<<dim3((N_NODES + 3) / 4), b256, 0, stream>>>(x, ln_g, ln_b, xln, N_NODES);
  // 2. vecw = vec * vln_w (bf16)
  vecw_kernel<<<dim3(2048), b256, 0, stream>>>(vec, vln_w, vecw, (size_t)NL * H / 8);
  // 3. big = vecw @ [Wvec|Wtrg|Wsrc], vec_dot fused; 2D grid (625 M-tiles x 4 ct-tiles)
  gemm_v4<__bf16, __bf16, true><<<dim3(625, 4), b256, 0, stream>>>(vecw, Wt, nullptr, big, vdot,
                                                                   NL, 384, 0);
  // 4. qkv = xln @ [Wq|Wk|Wv] + b (f32 out); grid 79x3
  gemm_v4<float, float, false><<<dim3(79, 3), b256, 0, stream>>>(xln, Wt + (size_t)640 * 128,
                                                                 bqkv, qkv, nullptr, N_NODES,
                                                                 384, 0);
  // 5. fm = silu(f_ij @ [Wdk|Wdv|Wf] + b); grid 500x3
  gemm_v4<float, __bf16, false><<<dim3(500, 3), b256, 0, stream>>>(f_ij, Wt + (size_t)1024 * 128,
                                                                   bfm, fm, nullptr, N_EDGES,
                                                                   384, 1);
  // 6. message -> vm (bf16)
  msg_kernel<<<dim3(N_EDGES / 2), b256, 0, stream>>>(qkv, fm, r_ij, ei, vm);
  // 7. s = silu(vm @ W_s + b); grid 500x2
  gemm_v4<__bf16, __bf16, false><<<dim3(500, 2), b256, 0, stream>>>(vm, Wt + (size_t)1408 * 128,
                                                                    b_s, s_buf, nullptr, N_EDGES,
                                                                    256, 1);
  // 8. gather into x_agg and dvec (no atomics)
  gather_kernel<<<dim3(N_NODES / 2), b256, 0, stream>>>(vm, s_buf, vecw, d_ij, ei, rowptr,
                                                        elist, x_agg, dvec);
  // 9. edge update -> df (reads big vt/vs + fm dfw)
  edgeupd_kernel<<<dim3(N_EDGES / 2), b256, 0, stream>>>(big, d_ij, fm, ei, df);
  // 10. o = x_agg @ W_o + b (f32; overwrites qkv: consumed in 6); grid 79x3
  gemm_v4<float, float, false><<<dim3(79, 3), b256, 0, stream>>>(x_agg, Wt + (size_t)1664 * 128,
                                                                 b_o, o_buf, nullptr, N_NODES,
                                                                 384, 0);
  // 11. final: dx, dvec += vec3*o1
  final_kernel<<<dim3(5000), b256, 0, stream>>>(o_buf, vdot, big, dx, dvec, N_NODES);
}

// Round 9
// 346.649 us; speedup vs baseline: 1.4235x; 1.0929x over previous
//
#include <hip/hip_runtime.h>
#include <hip/hip_bf16.h>
#include <math.h>

#define N_NODES 10000
#define N_EDGES 64000
#define H 128
#define L 8
#define NL (N_NODES * L)

typedef __attribute__((ext_vector_type(4))) float f32x4;
typedef __attribute__((ext_vector_type(8))) __bf16 bf16x8;

__device__ __forceinline__ float silu_f(float x) { return x / (1.f + __expf(-x)); }

// ---------------- LayerNorm: one wave per node ----------------
__global__ __launch_bounds__(256) void ln_kernel(const float* __restrict__ x,
                                                 const float* __restrict__ g,
                                                 const float* __restrict__ b,
                                                 float* __restrict__ out, int n_nodes) {
  int wave = threadIdx.x >> 6;
  int lane = threadIdx.x & 63;
  int n = blockIdx.x * 4 + wave;
  if (n >= n_nodes) return;
  const float* xr = x + (size_t)n * H;
  float a0 = xr[lane], a1 = xr[lane + 64];
  float s = a0 + a1;
#pragma unroll
  for (int off = 32; off >= 1; off >>= 1) s += __shfl_xor(s, off, 64);
  float mu = s * (1.f / H);
  float d0 = a0 - mu, d1 = a1 - mu;
  float v = d0 * d0 + d1 * d1;
#pragma unroll
  for (int off = 32; off >= 1; off >>= 1) v += __shfl_xor(v, off, 64);
  float rstd = rsqrtf(v * (1.f / H) + 1e-5f);
  float* orow = out + (size_t)n * H;
  orow[lane] = d0 * rstd * g[lane] + b[lane];
  orow[lane + 64] = d1 * rstd * g[lane + 64] + b[lane + 64];
}

// ---------------- vecw = vec * vln_w  -> bf16 ----------------
__global__ __launch_bounds__(256) void vecw_kernel(const float* __restrict__ vec,
                                                   const float* __restrict__ w,
                                                   __bf16* __restrict__ out, size_t total8) {
  size_t i = (size_t)blockIdx.x * blockDim.x + threadIdx.x;
  size_t stride = (size_t)gridDim.x * blockDim.x;
  for (; i < total8; i += stride) {
    size_t base = i * 8;
    f32x4 a = *(const f32x4*)(vec + base);
    f32x4 b = *(const f32x4*)(vec + base + 4);
    int c = (int)(base & 127);
    bf16x8 h;
    h[0] = (__bf16)(a[0] * w[c + 0]); h[1] = (__bf16)(a[1] * w[c + 1]);
    h[2] = (__bf16)(a[2] * w[c + 2]); h[3] = (__bf16)(a[3] * w[c + 3]);
    h[4] = (__bf16)(b[0] * w[c + 4]); h[5] = (__bf16)(b[1] * w[c + 5]);
    h[6] = (__bf16)(b[2] * w[c + 6]); h[7] = (__bf16)(b[3] * w[c + 7]);
    *(bf16x8*)(out + base) = h;
  }
}

// ---------------- weight convert into one [2048][128] bf16 table ----------------
// col map: [0,384) Wvec | [384,512) Wtrg | [512,640) Wsrc | [640,768) Wq | [768,896) Wk
//          | [896,1024) Wv | [1024,1152) Wdk | [1152,1280) Wdv | [1280,1408) Wf
//          | [1408,1664) Ws | [1664,2048) Wo
__global__ __launch_bounds__(256) void wconv_kernel(
    const float* __restrict__ Wvec, const float* __restrict__ Wq, const float* __restrict__ Wk,
    const float* __restrict__ Wv, const float* __restrict__ Wdk, const float* __restrict__ Wdv,
    const float* __restrict__ Ws, const float* __restrict__ Wtrg, const float* __restrict__ Wsrc,
    const float* __restrict__ Wf, const float* __restrict__ Wo,
    const float* __restrict__ bq, const float* __restrict__ bk, const float* __restrict__ bv,
    const float* __restrict__ bdk, const float* __restrict__ bdv, const float* __restrict__ bf,
    __bf16* __restrict__ Wt, float* __restrict__ bqkv, float* __restrict__ bfm) {
  int bid = blockIdx.x;
  int t = threadIdx.x;
  if (bid >= 256) {
    if (bid == 256) {
      if (t < 128) { bqkv[t] = bq[t]; bqkv[128 + t] = bk[t]; bqkv[256 + t] = bv[t]; }
    } else {
      if (t < 128) { bfm[t] = bdk[t]; bfm[128 + t] = bdv[t]; bfm[256 + t] = bf[t]; }
    }
    return;
  }
  int ct = bid >> 2, kt = bid & 3;
  int gc0 = ct * 32;
  const float* W; int ldw, sc0;
  if      (gc0 < 384)  { W = Wvec; ldw = 384; sc0 = gc0; }
  else if (gc0 < 512)  { W = Wtrg; ldw = 128; sc0 = gc0 - 384; }
  else if (gc0 < 640)  { W = Wsrc; ldw = 128; sc0 = gc0 - 512; }
  else if (gc0 < 768)  { W = Wq;   ldw = 128; sc0 = gc0 - 640; }
  else if (gc0 < 896)  { W = Wk;   ldw = 128; sc0 = gc0 - 768; }
  else if (gc0 < 1024) { W = Wv;   ldw = 128; sc0 = gc0 - 896; }
  else if (gc0 < 1152) { W = Wdk;  ldw = 128; sc0 = gc0 - 1024; }
  else if (gc0 < 1280) { W = Wdv;  ldw = 128; sc0 = gc0 - 1152; }
  else if (gc0 < 1408) { W = Wf;   ldw = 128; sc0 = gc0 - 1280; }
  else if (gc0 < 1664) { W = Ws;   ldw = 256; sc0 = gc0 - 1408; }
  else                 { W = Wo;   ldw = 384; sc0 = gc0 - 1664; }
  __shared__ float tile[32][33];
  int tx = t & 31, ty = t >> 5;
#pragma unroll
  for (int i = 0; i < 4; ++i)
    tile[ty + i * 8][tx] = W[(size_t)(kt * 32 + ty + i * 8) * ldw + sc0 + tx];
  __syncthreads();
#pragma unroll
  for (int i = 0; i < 4; ++i)
    Wt[(size_t)(gc0 + ty + i * 8) * 128 + kt * 32 + tx] = (__bf16)tile[tx][ty + i * 8];
}

// ---------------- MFMA GEMM v5: 2D grid (M-tile, ct-tile); one 128x128 tile per block ----------
// As-only LDS (32KB, swizzled). bf16-CT epilogue staged through LDS -> 16B coalesced stores.
// FUSE: blockIdx.y==0 computes ct0,ct1 -> vdot only; y>=1 computes ct=y+1, stores col (y-1)*128.
template <typename AT, typename CT, bool FUSE>
__global__ __launch_bounds__(256, 3) void gemm_v5(const AT* __restrict__ A,
                                                  const __bf16* __restrict__ Bt,
                                                  const float* __restrict__ bias,
                                                  CT* __restrict__ C,
                                                  float* __restrict__ vdot, int M, int ldc,
                                                  int act) {
  __shared__ __bf16 As[128 * 128];
  __shared__ __bf16 Cs[32 * 136];  // padded staging for vectorized C-store
  const int tid = threadIdx.x;
  const int lane = tid & 63;
  const int wave = tid >> 6;
  const int wm = wave >> 1, wn = wave & 1;
  const int row0 = blockIdx.x * 128;

  if constexpr (sizeof(AT) == 2) {
#pragma unroll
    for (int i = 0; i < 8; ++i) {
      int c = tid + i * 256;  // 16B chunk; LDS dest linear
      int row = c >> 4, k8 = c & 15;
      int k8s = k8 ^ (row & 7);  // inverse-swizzled source == read-side XOR
      const AT* src = A + (size_t)(row0 + row) * 128 + k8s * 8;
      __builtin_amdgcn_global_load_lds((const __attribute__((address_space(1))) void*)src,
                                       (__attribute__((address_space(3))) void*)(As + c * 8),
                                       16, 0, 0);
    }
  } else {
#pragma unroll
    for (int i = 0; i < 8; ++i) {
      int c = tid + i * 256;
      int row = c >> 4, k8 = c & 15;
      int gm = row0 + row;
      bf16x8 h = {};
      if (gm < M) {
        f32x4 f0 = *(const f32x4*)(A + (size_t)gm * 128 + k8 * 8);
        f32x4 f1 = *(const f32x4*)(A + (size_t)gm * 128 + k8 * 8 + 4);
        h[0] = (__bf16)f0[0]; h[1] = (__bf16)f0[1]; h[2] = (__bf16)f0[2]; h[3] = (__bf16)f0[3];
        h[4] = (__bf16)f1[0]; h[5] = (__bf16)f1[1]; h[6] = (__bf16)f1[2]; h[7] = (__bf16)f1[3];
      }
      int byte = (c * 16) ^ ((row & 7) << 4);
      *(bf16x8*)((char*)As + byte) = h;
    }
  }
  __syncthreads();

  const int y = blockIdx.y;

  if constexpr (FUSE) {
    if (y == 0) {
      // ct=0 (vec1) and ct=1 (vec2) -> vdot; per-ks B loads (VGPR budget)
      f32x4 pacc[4][4], acc[4][4];
#pragma unroll
      for (int mi = 0; mi < 4; ++mi)
#pragma unroll
        for (int ni = 0; ni < 4; ++ni) {
          pacc[mi][ni] = f32x4{0.f, 0.f, 0.f, 0.f};
          acc[mi][ni] = f32x4{0.f, 0.f, 0.f, 0.f};
        }
#pragma unroll
      for (int ct = 0; ct < 2; ++ct) {
        const __bf16* Bbase =
            Bt + ((size_t)(ct * 128 + wn * 64 + (lane & 15)) << 7) + ((lane >> 4) << 3);
#pragma unroll
        for (int ks = 0; ks < 4; ++ks) {
          bf16x8 b[4];
#pragma unroll
          for (int ni = 0; ni < 4; ++ni) b[ni] = *(const bf16x8*)(Bbase + (ni << 11) + (ks << 5));
          bf16x8 a[4];
#pragma unroll
          for (int mi = 0; mi < 4; ++mi) {
            int row = wm * 64 + mi * 16 + (lane & 15);
            int byte = (row * 256 + ks * 64 + ((lane >> 4) << 4)) ^ ((row & 7) << 4);
            a[mi] = *(const bf16x8*)((const char*)As + byte);
          }
          if (ct == 0) {
#pragma unroll
            for (int mi = 0; mi < 4; ++mi)
#pragma unroll
              for (int ni = 0; ni < 4; ++ni)
                pacc[mi][ni] =
                    __builtin_amdgcn_mfma_f32_16x16x32_bf16(a[mi], b[ni], pacc[mi][ni], 0, 0, 0);
          } else {
#pragma unroll
            for (int mi = 0; mi < 4; ++mi)
#pragma unroll
              for (int ni = 0; ni < 4; ++ni)
                acc[mi][ni] =
                    __builtin_amdgcn_mfma_f32_16x16x32_bf16(a[mi], b[ni], acc[mi][ni], 0, 0, 0);
          }
        }
      }
      // vdot[node][c] = sum over 8 L-rows of vec1*vec2
#pragma unroll
      for (int mi = 0; mi < 4; ++mi) {
#pragma unroll
        for (int ni = 0; ni < 4; ++ni) {
          float sr = pacc[mi][ni][0] * acc[mi][ni][0] + pacc[mi][ni][1] * acc[mi][ni][1] +
                     pacc[mi][ni][2] * acc[mi][ni][2] + pacc[mi][ni][3] * acc[mi][ni][3];
          sr += __shfl_xor(sr, 16, 64);
          if ((lane & 16) == 0) {
            int node = (row0 >> 3) + wm * 8 + mi * 2 + (lane >> 5);
            int col = wn * 64 + ni * 16 + (lane & 15);
            vdot[(size_t)node * 128 + col] = sr;
          }
        }
      }
      return;
    }
  }

  const int ct = FUSE ? y + 1 : y;
  const int cstore = FUSE ? (y - 1) * 128 : y * 128;

  // hoist all 16 B fragments (one wait; weights L2-hot)
  const __bf16* Bbase =
      Bt + ((size_t)(ct * 128 + wn * 64 + (lane & 15)) << 7) + ((lane >> 4) << 3);
  bf16x8 b[4][4];
#pragma unroll
  for (int ks = 0; ks < 4; ++ks)
#pragma unroll
    for (int ni = 0; ni < 4; ++ni) b[ks][ni] = *(const bf16x8*)(Bbase + (ni << 11) + (ks << 5));

  f32x4 acc[4][4];
#pragma unroll
  for (int mi = 0; mi < 4; ++mi)
#pragma unroll
    for (int ni = 0; ni < 4; ++ni) acc[mi][ni] = f32x4{0.f, 0.f, 0.f, 0.f};

#pragma unroll
  for (int ks = 0; ks < 4; ++ks) {
    bf16x8 a[4];
#pragma unroll
    for (int mi = 0; mi < 4; ++mi) {
      int row = wm * 64 + mi * 16 + (lane & 15);
      int byte = (row * 256 + ks * 64 + ((lane >> 4) << 4)) ^ ((row & 7) << 4);
      a[mi] = *(const bf16x8*)((const char*)As + byte);
    }
#pragma unroll
    for (int mi = 0; mi < 4; ++mi)
#pragma unroll
      for (int ni = 0; ni < 4; ++ni)
        acc[mi][ni] =
            __builtin_amdgcn_mfma_f32_16x16x32_bf16(a[mi], b[ks][ni], acc[mi][ni], 0, 0, 0);
  }

  if constexpr (sizeof(CT) == 2) {
    // staged epilogue: acc -> LDS (padded) -> 16B coalesced stores (full 128 cols!)
#pragma unroll
    for (int mi = 0; mi < 4; ++mi) {
      __syncthreads();  // previous stage consumed
      int rl = (wm << 4) | ((lane >> 4) << 2);
#pragma unroll
      for (int ni = 0; ni < 4; ++ni) {
        int col = wn * 64 + ni * 16 + (lane & 15);
        float bv = bias ? bias[ct * 128 + col] : 0.f;
#pragma unroll
        for (int r = 0; r < 4; ++r) {
          float xv = acc[mi][ni][r] + bv;
          if (act) xv = silu_f(xv);
          Cs[(rl + r) * 136 + col] = (__bf16)xv;
        }
      }
      __syncthreads();
      // 32 rows x 16 chunks of 8 bf16 = 512 stores; 2 per thread
#pragma unroll
      for (int rr = 0; rr < 2; ++rr) {
        int row = (tid >> 4) + rr * 16;
        int chunk = tid & 15;
        bf16x8 v = *(const bf16x8*)(Cs + row * 136 + chunk * 8);
        int grow = row0 + (row >> 4) * 64 + mi * 16 + (row & 15);
        if (grow < M)
          *(bf16x8*)(C + (size_t)grow * ldc + cstore + chunk * 8) = v;
      }
    }
  } else {
#pragma unroll
    for (int mi = 0; mi < 4; ++mi) {
      int rbase = row0 + wm * 64 + mi * 16 + ((lane >> 4) << 2);
#pragma unroll
      for (int ni = 0; ni < 4; ++ni) {
        int gcol = cstore + wn * 64 + ni * 16 + (lane & 15);
        float bv = bias ? bias[ct * 128 + wn * 64 + ni * 16 + (lane & 15)] : 0.f;
#pragma unroll
        for (int r = 0; r < 4; ++r) {
          int grow = rbase + r;
          if (grow < M) {
            float xv = acc[mi][ni][r] + bv;
            if (act) xv = silu_f(xv);
            C[(size_t)grow * ldc + gcol] = (CT)xv;
          }
        }
      }
    }
  }
}

// ---------------- message: attn + vm per edge (qkv bf16 [N][384]; dk/dv = fm cols 0..255) ----------
__global__ __launch_bounds__(256) void msg_kernel(const __bf16* __restrict__ qkv,
                                                  const __bf16* __restrict__ fm,
                                                  const float* __restrict__ r_ij,
                                                  const int* __restrict__ ei,
                                                  __bf16* __restrict__ vm) {
  int e = blockIdx.x * 2 + (threadIdx.x >> 7);
  int h = threadIdx.x & 127;
  int src = ei[e], dst = ei[N_EDGES + e];
  float qv = (float)qkv[(size_t)dst * 384 + h];
  float kv = (float)qkv[(size_t)src * 384 + 128 + h];
  float vv = (float)qkv[(size_t)src * 384 + 256 + h];
  float t = qv * kv * (float)fm[(size_t)e * 384 + h];
#pragma unroll
  for (int off = 8; off >= 1; off >>= 1) t += __shfl_xor(t, off, 16);
  float r = r_ij[e];
  float cut = 0.5f * (__cosf(0.6283185307f * r) + 1.f);
  cut = (r < 5.f) ? cut : 0.f;
  float attn = silu_f(t) * cut;
  vm[(size_t)e * H + h] = (__bf16)(vv * (float)fm[(size_t)e * 384 + 128 + h] * attn);
}

// ---------------- CSR build: histogram, scan, fill ----------------
__global__ __launch_bounds__(256) void hist_kernel(const int* __restrict__ ei,
                                                   int* __restrict__ cnt) {
  int e = blockIdx.x * 256 + threadIdx.x;
  if (e < N_EDGES) atomicAdd(&cnt[ei[N_EDGES + e]], 1);
}

__global__ __launch_bounds__(1024) void scan_kernel(const int* __restrict__ cnt,
                                                    int* __restrict__ rowptr) {
  __shared__ int wsum[16];
  int t = threadIdx.x;
  int base = t * 10;
  int local[10];
  int s = 0;
#pragma unroll
  for (int i = 0; i < 10; ++i) {
    int v = (base + i < N_NODES) ? cnt[base + i] : 0;
    local[i] = s;
    s += v;
  }
  int lane = t & 63, wave = t >> 6;
  int inc = s;
#pragma unroll
  for (int off = 1; off < 64; off <<= 1) {
    int u = __shfl_up(inc, off, 64);
    if (lane >= off) inc += u;
  }
  if (lane == 63) wsum[wave] = inc;
  __syncthreads();
  if (t == 0) {
    int acc = 0;
#pragma unroll
    for (int w = 0; w < 16; ++w) { int v = wsum[w]; wsum[w] = acc; acc += v; }
  }
  __syncthreads();
  int excl = inc - s + wsum[wave];
#pragma unroll
  for (int i = 0; i < 10; ++i)
    if (base + i <= N_NODES) rowptr[base + i] = excl + local[i];
}

__global__ __launch_bounds__(256) void fill_kernel(const int* __restrict__ ei,
                                                   const int* __restrict__ rowptr,
                                                   int* __restrict__ cursor,
                                                   int* __restrict__ elist) {
  int e = blockIdx.x * 256 + threadIdx.x;
  if (e < N_EDGES) {
    int d = ei[N_EDGES + e];
    int p = atomicAdd(&cursor[d], 1);
    elist[rowptr[d] + p] = e;
  }
}

// ---------------- gather: x_agg = Σ vm ; dvec = Σ vec_m (no atomics) ----------------
__global__ __launch_bounds__(256) void gather_kernel(const __bf16* __restrict__ vm,
                                                     const __bf16* __restrict__ s,
                                                     const __bf16* __restrict__ vecw,
                                                     const float* __restrict__ d_ij,
                                                     const int* __restrict__ ei,
                                                     const int* __restrict__ rowptr,
                                                     const int* __restrict__ elist,
                                                     float* __restrict__ x_agg,
                                                     float* __restrict__ dvec) {
  int n = blockIdx.x * 2 + (threadIdx.x >> 7);
  int h = threadIdx.x & 127;
  if (n >= N_NODES) return;
  int beg = rowptr[n], end = rowptr[n + 1];
  float ax = 0.f;
  float av[L] = {};
  for (int p = beg; p < end; ++p) {
    int e = elist[p];
    int src = ei[e];
    ax += (float)vm[(size_t)e * H + h];
    float s1 = (float)s[(size_t)e * 256 + h];
    float s2 = (float)s[(size_t)e * 256 + 128 + h];
    const __bf16* vrow = vecw + (size_t)src * L * H + h;
    const float* dd = d_ij + (size_t)e * L;
#pragma unroll
    for (int l = 0; l < L; l++) av[l] += (float)vrow[l * H] * s1 + s2 * dd[l];
  }
  x_agg[(size_t)n * H + h] = ax;
  float* drow = dvec + (size_t)n * L * H + h;
#pragma unroll
  for (int l = 0; l < L; l++) drow[l * H] = av[l];
}

// ---------------- edge update (big [NL][384]: vec3 @0, vt @128, vs @256; dfw = fm @256) ----------------
__global__ __launch_bounds__(256) void edgeupd_kernel(const __bf16* __restrict__ big,
                                                      const float* __restrict__ d_ij,
                                                      const __bf16* __restrict__ fm,
                                                      const int* __restrict__ ei,
                                                      float* __restrict__ df) {
  int e = blockIdx.x * 2 + (threadIdx.x >> 7);
  int h = threadIdx.x & 127;
  int src = ei[e], dst = ei[N_EDGES + e];
  float d[L];
  float sd2 = 0.f;
#pragma unroll
  for (int l = 0; l < L; l++) {
    d[l] = d_ij[(size_t)e * L + l];
    sd2 += d[l] * d[l];
  }
  const __bf16* arow = big + (size_t)dst * 8 * 384 + 128 + h;
  const __bf16* brow = big + (size_t)src * 8 * 384 + 256 + h;
  float dot = 0.f, p1 = 0.f, p2 = 0.f;
#pragma unroll
  for (int l = 0; l < L; l++) {
    float a = (float)arow[l * 384], bb = (float)brow[l * 384];
    dot += a * bb;
    p1 += a * d[l];
    p2 += bb * d[l];
  }
  float wdot = dot - p1 * p2 * (2.f - sd2);
  df[(size_t)e * H + h] = (float)fm[(size_t)e * 384 + 256 + h] * wdot;
}

// ---------------- final node update (vec3 = big cols 0..127) ----------------
__global__ __launch_bounds__(256) void final_kernel(const float* __restrict__ o,
                                                    const float* __restrict__ vdot,
                                                    const __bf16* __restrict__ big,
                                                    float* __restrict__ dx,
                                                    float* __restrict__ dvec, int n_nodes) {
  int n = blockIdx.x * 2 + (threadIdx.x >> 7);
  int h = threadIdx.x & 127;
  if (n >= n_nodes) return;
  float o1 = o[(size_t)n * 384 + h];
  float o2 = o[(size_t)n * 384 + 128 + h];
  float o3 = o[(size_t)n * 384 + 256 + h];
  dx[(size_t)n * H + h] = vdot[(size_t)n * H + h] * o2 + o3;
  float* drow = dvec + (size_t)n * L * H + h;
  const __bf16* v3 = big + (size_t)n * 8 * 384 + h;
#pragma unroll
  for (int l = 0; l < L; l++) drow[l * H] += (float)v3[l * 384] * o1;
}

extern "C" void kernel_launch(void* const* d_in, const int* in_sizes, int n_in, void* d_out,
                              int out_size, void* d_ws, size_t ws_size, hipStream_t stream) {
  const float* x = (const float*)d_in[0];
  const float* vec = (const float*)d_in[1];
  const float* f_ij = (const float*)d_in[2];
  const float* d_ij = (const float*)d_in[3];
  const float* r_ij = (const float*)d_in[4];
  const int* ei = (const int*)d_in[5];
  const float* ln_g = (const float*)d_in[6];
  const float* ln_b = (const float*)d_in[7];
  const float* vln_w = (const float*)d_in[8];
  const float* W_vec = (const float*)d_in[9];
  const float* W_q = (const float*)d_in[10];
  const float* b_q = (const float*)d_in[11];
  const float* W_k = (const float*)d_in[12];
  const float* b_k = (const float*)d_in[13];
  const float* W_v = (const float*)d_in[14];
  const float* b_v = (const float*)d_in[15];
  const float* W_dk = (const float*)d_in[16];
  const float* b_dk = (const float*)d_in[17];
  const float* W_dv = (const float*)d_in[18];
  const float* b_dv = (const float*)d_in[19];
  const float* W_s = (const float*)d_in[20];
  const float* b_s = (const float*)d_in[21];
  const float* W_f = (const float*)d_in[22];
  const float* b_f = (const float*)d_in[23];
  const float* W_src = (const float*)d_in[24];
  const float* W_trg = (const float*)d_in[25];
  const float* W_o = (const float*)d_in[26];
  const float* b_o = (const float*)d_in[27];

  float* out = (float*)d_out;
  float* dx = out;
  float* dvec = out + (size_t)N_NODES * H;
  float* df = dvec + (size_t)N_NODES * L * H;

  // ---- workspace plan (~207 MB; offsets in f32 slots) ----
  float* ws = (float*)d_ws;
  __bf16* vecw = (__bf16*)ws;                 // NL*128 bf16
  __bf16* big = (__bf16*)(ws + 5120000);      // NL*384 bf16: [vec3 128 | vt 128 | vs 128]
  __bf16* fm = (__bf16*)(ws + 20480000);      // E*384 bf16: [dk | dv | dfw]
  __bf16* vm = (__bf16*)(ws + 32768000);      // E*128 bf16
  __bf16* s_buf = (__bf16*)(ws + 36864000);   // E*256 bf16
  __bf16* qkv = (__bf16*)(ws + 45056000);     // N*384 bf16 (region reused as o_buf f32)
  float* xln = ws + 48896000;                 // N*128 f32 (reused as x_agg)
  float* vdot = ws + 50176000;                // N*128 f32
  __bf16* Wt = (__bf16*)(ws + 51456000);      // [2048][128] bf16
  float* bqkv = ws + 51456000 + 131072;       // 384
  float* bfm = bqkv + 384;                    // 384
  int* rowptr = (int*)(bfm + 384);            // 10,001
  int* elist = rowptr + 10001;                // 64,000
  int* cnt = elist + 64000;                   // 10,000
  int* cursor = cnt + 10000;                  // 10,000

  float* o_buf = ws + 45056000;  // overwrites qkv after it's consumed (step 6)
  float* x_agg = xln;

  dim3 b256(256);

  // CSR build (depends only on ei)
  hipMemsetAsync(cnt, 0, N_NODES * sizeof(int), stream);
  hipMemsetAsync(cursor, 0, N_NODES * sizeof(int), stream);
  hist_kernel<<<dim3((N_EDGES + 255) / 256), b256, 0, stream>>>(ei, cnt);
  scan_kernel<<<dim3(1), dim3(1024), 0, stream>>>(cnt, rowptr);
  fill_kernel<<<dim3((N_EDGES + 255) / 256), b256, 0, stream>>>(ei, rowptr, cursor, elist);

  // 0. weight convert/transpose + bias concat
  wconv_kernel<<<dim3(258), b256, 0, stream>>>(W_vec, W_q, W_k, W_v, W_dk, W_dv, W_s, W_trg,
                                               W_src, W_f, W_o, b_q, b_k, b_v, b_dk, b_dv, b_f,
                                               Wt, bqkv, bfm);
  // 1. x_ln = layernorm(x)
  ln_kernel<<<dim3((N_NODES + 3) / 4), b256, 0, stream>>>(x, ln_g, ln_b, xln, N_NODES);
  // 2. vecw = vec * vln_w (bf16)
  vecw_kernel<<<dim3(2048), b256, 0, stream>>>(vec, vln_w, vecw, (size_t)NL * H / 8);
  // 3. big = vecw @ [Wvec|Wtrg|Wsrc], vec_dot fused; 2D grid (625 M-tiles x 4 ct-tiles)
  gemm_v5<__bf16, __bf16, true><<<dim3(625, 4), b256, 0, stream>>>(vecw, Wt, nullptr, big, vdot,
                                                                   NL, 384, 0);
  // 4. qkv = xln @ [Wq|Wk|Wv] + b (bf16 out); grid 79x3
  gemm_v5<float, __bf16, false><<<dim3(79, 3), b256, 0, stream>>>(xln, Wt + (size_t)640 * 128,
                                                                  bqkv, qkv, nullptr, N_NODES,
                                                                  384, 0);
  // 5. fm = silu(f_ij @ [Wdk|Wdv|Wf] + b); grid 500x3
  gemm_v5<float, __bf16, false><<<dim3(500, 3), b256, 0, stream>>>(f_ij, Wt + (size_t)1024 * 128,
                                                                   bfm, fm, nullptr, N_EDGES,
                                                                   384, 1);
  // 6. message -> vm (bf16)
  msg_kernel<<<dim3(N_EDGES / 2), b256, 0, stream>>>(qkv, fm, r_ij, ei, vm);
  // 7. s = silu(vm @ W_s + b); grid 500x2
  gemm_v5<__bf16, __bf16, false><<<dim3(500, 2), b256, 0, stream>>>(vm, Wt + (size_t)1408 * 128,
                                                                    b_s, s_buf, nullptr, N_EDGES,
                                                                    256, 1);
  // 8. gather into x_agg and dvec (no atomics)
  gather_kernel<<<dim3(N_NODES / 2), b256, 0, stream>>>(vm, s_buf, vecw, d_ij, ei, rowptr,
                                                        elist, x_agg, dvec);
  // 9. edge update -> df (reads big vt/vs + fm dfw)
  edgeupd_kernel<<<dim3(N_EDGES / 2), b256, 0, stream>>>(big, d_ij, fm, ei, df);
  // 10. o = x_agg @ W_o + b (f32; overwrites qkv region: consumed in 6); grid 79x3
  gemm_v5<float, float, false><<<dim3(79, 3), b256, 0, stream>>>(x_agg, Wt + (size_t)1664 * 128,
                                                                 b_o, o_buf, nullptr, N_NODES,
                                                                 384, 0);
  // 11. final: dx, dvec += vec3*o1
  final_kernel<<<dim3(5000), b256, 0, stream>>>(o_buf, vdot, big, dx, dvec, N_NODES);
}